// Round 2
// baseline (9861.853 us; speedup 1.0000x reference)
//
#include <hip/hip_runtime.h>
#include <hip/hip_bf16.h>
#include <cfloat>

#define N_NODES 50000
#define N_EDGES 800000
#define E_TOT   850000   /* edges + self-loops */
#define NEG_SLOPE 0.2f
#define SM_EPS 1e-16f

// float atomic max via int ordering trick (addr init'd to a finite float, e.g. -FLT_MAX)
__device__ __forceinline__ void atomicMaxF(float* addr, float val) {
    if (val >= 0.0f) atomicMax((int*)addr, __float_as_int(val));
    else             atomicMin((unsigned int*)addr, (unsigned int)__float_as_int(val));
}

__global__ void fill_kernel(float* __restrict__ p, float v, int n) {
    int i = blockIdx.x * blockDim.x + threadIdx.x;
    if (i < n) p[i] = v;
}

// Detect edge_index storage: int64 (odd 32-bit words all zero, ids<50000) vs int32.
// Writes flag: 1 = int32 layout, 0 = int64 layout.
__global__ void detect_layout(const int* __restrict__ ei, int* __restrict__ flag) {
    __shared__ int any;
    if (threadIdx.x == 0) any = 0;
    __syncthreads();
    int acc = 0;
    // scan odd words of the first 4096 "int64 slots"
    for (int i = threadIdx.x; i < 4096; i += blockDim.x) acc |= ei[2 * i + 1];
    if (acc) atomicOr(&any, 1);
    __syncthreads();
    if (threadIdx.x == 0) *flag = any ? 1 : 0;
}

__global__ void convert_edges(const int* __restrict__ ei, const int* __restrict__ flag,
                              int* __restrict__ src, int* __restrict__ dst) {
    int e = blockIdx.x * blockDim.x + threadIdx.x;
    if (e >= N_EDGES) return;
    if (*flag) {           // int32 layout: [src[E], dst[E]]
        src[e] = ei[e];
        dst[e] = ei[N_EDGES + e];
    } else {               // int64 layout: little-endian lo words
        src[e] = ei[2 * e];
        dst[e] = ei[2 * N_EDGES + 2 * e];
    }
}

__device__ __forceinline__ void edge_src_dst(const int* __restrict__ srcA, const int* __restrict__ dstA,
                                             int e, int& src, int& dst) {
    if (e < N_EDGES) { src = srcA[e]; dst = dstA[e]; }
    else             { src = e - N_EDGES; dst = src; }
}

// C[M,N] = A[M,128] * B[128,N], fp32. One row per block, blockDim = N.
__global__ void gemm_row(const float* __restrict__ A, const float* __restrict__ B,
                         float* __restrict__ C, int N) {
    __shared__ float arow[128];
    int m = blockIdx.x;
    int j = threadIdx.x;
    for (int k = j; k < 128; k += blockDim.x) arow[k] = A[(size_t)m * 128 + k];
    __syncthreads();
    float acc = 0.0f;
    #pragma unroll 4
    for (int k = 0; k < 128; ++k) acc += arow[k] * B[(size_t)k * N + j];
    C[(size_t)m * N + j] = acc;
}

// ---------------- Layer 1 (H=8, C=16) ----------------

__global__ void edge_logit1(const int* __restrict__ srcA, const int* __restrict__ dstA,
                            const float* __restrict__ xl, const float* __restrict__ xr,
                            const float* __restrict__ att,
                            float* __restrict__ logit, float* __restrict__ m) {
    int idx = blockIdx.x * blockDim.x + threadIdx.x;
    if (idx >= E_TOT * 8) return;
    int e = idx >> 3, h = idx & 7;
    int src, dst; edge_src_dst(srcA, dstA, e, src, dst);
    const float* pl = xl + (size_t)src * 128 + h * 16;
    const float* pr = xr + (size_t)dst * 128 + h * 16;
    float acc = 0.0f;
    #pragma unroll
    for (int c = 0; c < 16; ++c) {
        float v = pl[c] + pr[c];
        v = v > 0.0f ? v : NEG_SLOPE * v;
        acc += att[h * 16 + c] * v;
    }
    logit[idx] = acc;
    atomicMaxF(&m[dst * 8 + h], acc);
}

__global__ void expsum1(const int* __restrict__ srcA, const int* __restrict__ dstA,
                        const float* __restrict__ m,
                        float* __restrict__ p, float* __restrict__ s) {
    int idx = blockIdx.x * blockDim.x + threadIdx.x;
    if (idx >= E_TOT * 8) return;
    int e = idx >> 3, h = idx & 7;
    int src, dst; edge_src_dst(srcA, dstA, e, src, dst);
    float v = __expf(p[idx] - m[dst * 8 + h]);
    p[idx] = v;
    atomicAdd(&s[dst * 8 + h], v);
}

__global__ void agg1(const int* __restrict__ srcA, const int* __restrict__ dstA,
                     const float* __restrict__ p, const float* __restrict__ xl,
                     float* __restrict__ acc) {
    int idx = blockIdx.x * blockDim.x + threadIdx.x;
    if (idx >= E_TOT * 8) return;
    int e = idx >> 3, h = idx & 7;
    int src, dst; edge_src_dst(srcA, dstA, e, src, dst);
    float pv = p[idx];
    const float* pl = xl + (size_t)src * 128 + h * 16;
    float* pa = acc + (size_t)dst * 128 + h * 16;
    #pragma unroll
    for (int c = 0; c < 16; ++c) atomicAdd(&pa[c], pv * pl[c]);
}

__global__ void fin1(const float* __restrict__ s, const float* __restrict__ b1,
                     float* __restrict__ acc) {
    int idx = blockIdx.x * blockDim.x + threadIdx.x;
    if (idx >= N_NODES * 128) return;
    int n = idx >> 7, j = idx & 127, h = j >> 4;
    float v = acc[idx] / (s[n * 8 + h] + SM_EPS) + b1[j];
    acc[idx] = v > 0.0f ? v : 0.0f;   // relu in place -> h
}

// ---------------- Layer 2 (H=1, C=64) ----------------

__global__ void edge_logit2(const int* __restrict__ srcA, const int* __restrict__ dstA,
                            const float* __restrict__ xl, const float* __restrict__ xr,
                            const float* __restrict__ att,
                            float* __restrict__ logit, float* __restrict__ m) {
    int e = blockIdx.x * blockDim.x + threadIdx.x;
    if (e >= E_TOT) return;
    int src, dst; edge_src_dst(srcA, dstA, e, src, dst);
    const float* pl = xl + (size_t)src * 64;
    const float* pr = xr + (size_t)dst * 64;
    float acc = 0.0f;
    #pragma unroll 8
    for (int c = 0; c < 64; ++c) {
        float v = pl[c] + pr[c];
        v = v > 0.0f ? v : NEG_SLOPE * v;
        acc += att[c] * v;
    }
    logit[e] = acc;
    atomicMaxF(&m[dst], acc);
}

__global__ void expsum2(const int* __restrict__ srcA, const int* __restrict__ dstA,
                        const float* __restrict__ m,
                        float* __restrict__ p, float* __restrict__ s) {
    int e = blockIdx.x * blockDim.x + threadIdx.x;
    if (e >= E_TOT) return;
    int src, dst; edge_src_dst(srcA, dstA, e, src, dst);
    float v = __expf(p[e] - m[dst]);
    p[e] = v;
    atomicAdd(&s[dst], v);
}

__global__ void agg2(const int* __restrict__ srcA, const int* __restrict__ dstA,
                     const float* __restrict__ p, const float* __restrict__ xl,
                     float* __restrict__ acc) {
    int idx = blockIdx.x * blockDim.x + threadIdx.x;
    if (idx >= E_TOT * 4) return;
    int e = idx >> 2, q = idx & 3;
    int src, dst; edge_src_dst(srcA, dstA, e, src, dst);
    float pv = p[e];
    const float* pl = xl + (size_t)src * 64 + q * 16;
    float* pa = acc + (size_t)dst * 64 + q * 16;
    #pragma unroll
    for (int c = 0; c < 16; ++c) atomicAdd(&pa[c], pv * pl[c]);
}

__global__ void fin2(const float* __restrict__ s, const float* __restrict__ b2,
                     float* __restrict__ acc, float* __restrict__ out_emb) {
    int idx = blockIdx.x * blockDim.x + threadIdx.x;
    if (idx >= N_NODES * 64) return;
    int n = idx >> 6, c = idx & 63;
    float v = acc[idx] / (s[n] + SM_EPS) + b2[c];
    acc[idx] = v;           // fp32 emb for classifier
    out_emb[idx] = v;       // emb output
}

// ---------------- Classifier ----------------
// logits = relu(emb @ Wc1 + bc1) @ Wc2 + bc2 ;  Wc1 [64,128], Wc2 [128,2]
__global__ void classifier(const float* __restrict__ emb, const float* __restrict__ Wc1,
                           const float* __restrict__ bc1, const float* __restrict__ Wc2,
                           const float* __restrict__ bc2, float* __restrict__ out_logits) {
    __shared__ float er[64];
    __shared__ float t[128];
    int n = blockIdx.x, j = threadIdx.x;
    if (j < 64) er[j] = emb[(size_t)n * 64 + j];
    __syncthreads();
    float acc = bc1[j];
    #pragma unroll 8
    for (int k = 0; k < 64; ++k) acc += er[k] * Wc1[k * 128 + j];
    t[j] = acc > 0.0f ? acc : 0.0f;
    __syncthreads();
    if (j < 2) {
        float a2 = bc2[j];
        for (int k = 0; k < 128; ++k) a2 += t[k] * Wc2[k * 2 + j];
        out_logits[(size_t)n * 2 + j] = a2;
    }
}

extern "C" void kernel_launch(void* const* d_in, const int* in_sizes, int n_in,
                              void* d_out, int out_size, void* d_ws, size_t ws_size,
                              hipStream_t stream) {
    const float* x    = (const float*)d_in[0];
    const int*   ei   = (const int*)d_in[1];
    // d_in[2] edge_attr: dead code in reference
    const float* Wl1  = (const float*)d_in[3];
    const float* Wr1  = (const float*)d_in[4];
    const float* att1 = (const float*)d_in[5];
    const float* b1   = (const float*)d_in[6];
    const float* Wl2  = (const float*)d_in[7];
    const float* Wr2  = (const float*)d_in[8];
    const float* att2 = (const float*)d_in[9];
    const float* b2   = (const float*)d_in[10];
    // d_in[11..14] edge encoder: dead code
    const float* Wc1  = (const float*)d_in[15];
    const float* bc1  = (const float*)d_in[16];
    const float* Wc2  = (const float*)d_in[17];
    const float* bc2  = (const float*)d_in[18];

    float* ws = (float*)d_ws;
    int*   srcA = (int*)ws;                 // 0.80M words
    int*   dstA = (int*)(ws + 800000);      // 0.80M
    int*   flag = (int*)(ws + 1600000);     // 1
    float* xl1  = ws + 1700000;             // 6.40M  (layer 2: xl2 in first 3.2M)
    float* xr1  = ws + 8100000;             // 6.40M  (layer 2: xr2)
    float* acc1 = ws + 14500000;            // 6.40M  (becomes h)
    float* p1   = ws + 20900000;            // 6.80M  (layer 2: p2 in first 0.85M)
    float* m1   = ws + 27700000;            // 0.40M
    float* s1   = ws + 28100000;            // 0.40M
    float* acc2 = ws + 28500000;            // 3.20M  (becomes fp32 emb)
    // total ≈ 31.7M floats ≈ 127 MB

    float* out_emb    = (float*)d_out;
    float* out_logits = out_emb + (size_t)N_NODES * 64;

    const int B = 256;
    #define GRID(n) (((n) + B - 1) / B)

    detect_layout<<<1, 256, 0, stream>>>(ei, flag);
    convert_edges<<<GRID(N_EDGES), B, 0, stream>>>(ei, flag, srcA, dstA);

    // ---- layer 1 ----
    gemm_row<<<N_NODES, 128, 0, stream>>>(x, Wl1, xl1, 128);
    gemm_row<<<N_NODES, 128, 0, stream>>>(x, Wr1, xr1, 128);
    fill_kernel<<<GRID(N_NODES * 8), B, 0, stream>>>(m1, -FLT_MAX, N_NODES * 8);
    fill_kernel<<<GRID(N_NODES * 8), B, 0, stream>>>(s1, 0.0f, N_NODES * 8);
    fill_kernel<<<GRID(N_NODES * 128), B, 0, stream>>>(acc1, 0.0f, N_NODES * 128);
    edge_logit1<<<GRID(E_TOT * 8), B, 0, stream>>>(srcA, dstA, xl1, xr1, att1, p1, m1);
    expsum1<<<GRID(E_TOT * 8), B, 0, stream>>>(srcA, dstA, m1, p1, s1);
    agg1<<<GRID(E_TOT * 8), B, 0, stream>>>(srcA, dstA, p1, xl1, acc1);
    fin1<<<GRID(N_NODES * 128), B, 0, stream>>>(s1, b1, acc1);

    // ---- layer 2 ----
    gemm_row<<<N_NODES, 64, 0, stream>>>(acc1, Wl2, xl1, 64);
    gemm_row<<<N_NODES, 64, 0, stream>>>(acc1, Wr2, xr1, 64);
    fill_kernel<<<GRID(N_NODES), B, 0, stream>>>(m1, -FLT_MAX, N_NODES);
    fill_kernel<<<GRID(N_NODES), B, 0, stream>>>(s1, 0.0f, N_NODES);
    fill_kernel<<<GRID(N_NODES * 64), B, 0, stream>>>(acc2, 0.0f, N_NODES * 64);
    edge_logit2<<<GRID(E_TOT), B, 0, stream>>>(srcA, dstA, xl1, xr1, att2, p1, m1);
    expsum2<<<GRID(E_TOT), B, 0, stream>>>(srcA, dstA, m1, p1, s1);
    agg2<<<GRID(E_TOT * 4), B, 0, stream>>>(srcA, dstA, p1, xl1, acc2);
    fin2<<<GRID(N_NODES * 64), B, 0, stream>>>(s1, b2, acc2, out_emb);

    // ---- classifier ----
    classifier<<<N_NODES, 128, 0, stream>>>(acc2, Wc1, bc1, Wc2, bc2, out_logits);
    #undef GRID
}

// Round 3
// 1175.905 us; speedup vs baseline: 8.3866x; 8.3866x over previous
//
#include <hip/hip_runtime.h>
#include <hip/hip_bf16.h>
#include <cfloat>

#define N_NODES 50000
#define N_EDGES 800000
#define E_TOT   850000   /* edges + self-loops */
#define NEG_SLOPE 0.2f
#define SM_EPS 1e-16f

__global__ void fill_int(int* __restrict__ p, int v, int n) {
    int i = blockIdx.x * blockDim.x + threadIdx.x;
    if (i < n) p[i] = v;
}

// Detect edge_index storage: int64 (odd 32-bit words all zero, ids<50000) vs int32.
__global__ void detect_layout(const int* __restrict__ ei, int* __restrict__ flag) {
    __shared__ int any;
    if (threadIdx.x == 0) any = 0;
    __syncthreads();
    int acc = 0;
    for (int i = threadIdx.x; i < 4096; i += blockDim.x) acc |= ei[2 * i + 1];
    if (acc) atomicOr(&any, 1);
    __syncthreads();
    if (threadIdx.x == 0) *flag = any ? 1 : 0;
}

__global__ void convert_edges(const int* __restrict__ ei, const int* __restrict__ flag,
                              int* __restrict__ src, int* __restrict__ dst) {
    int e = blockIdx.x * blockDim.x + threadIdx.x;
    if (e >= N_EDGES) return;
    if (*flag) {           // int32 layout
        src[e] = ei[e];
        dst[e] = ei[N_EDGES + e];
    } else {               // int64 layout: lo words
        src[e] = ei[2 * e];
        dst[e] = ei[2 * N_EDGES + 2 * e];
    }
}

__device__ __forceinline__ void edge_src_dst(const int* __restrict__ srcA, const int* __restrict__ dstA,
                                             int e, int& src, int& dst) {
    if (e < N_EDGES) { src = srcA[e]; dst = dstA[e]; }
    else             { src = e - N_EDGES; dst = src; }
}

__global__ void deg_count(const int* __restrict__ srcA, const int* __restrict__ dstA,
                          int* __restrict__ deg) {
    int e = blockIdx.x * blockDim.x + threadIdx.x;
    if (e >= E_TOT) return;
    int src, dst; edge_src_dst(srcA, dstA, e, src, dst);
    atomicAdd(&deg[dst], 1);
}

// Single-block exclusive scan of deg[N_NODES] -> rowptr[N_NODES+1]. 1024 threads.
__global__ void scan_rowptr(const int* __restrict__ deg, int* __restrict__ rowptr) {
    __shared__ int partial[1024];
    const int CH = (N_NODES + 1023) / 1024;   // 49
    int t = threadIdx.x;
    int base = t * CH;
    int sum = 0;
    for (int i = 0; i < CH; ++i) { int idx = base + i; if (idx < N_NODES) sum += deg[idx]; }
    partial[t] = sum;
    __syncthreads();
    for (int off = 1; off < 1024; off <<= 1) {
        int v = (t >= off) ? partial[t - off] : 0;
        __syncthreads();
        partial[t] += v;
        __syncthreads();
    }
    int run = (t == 0) ? 0 : partial[t - 1];
    for (int i = 0; i < CH; ++i) {
        int idx = base + i;
        if (idx < N_NODES) { rowptr[idx] = run; run += deg[idx]; }
    }
    if (t == 1023) rowptr[N_NODES] = partial[1023];
}

__global__ void scatter_edges(const int* __restrict__ srcA, const int* __restrict__ dstA,
                              const int* __restrict__ rowptr, int* __restrict__ cnt,
                              int* __restrict__ esrc, int* __restrict__ epos) {
    int e = blockIdx.x * blockDim.x + threadIdx.x;
    if (e >= E_TOT) return;
    int src, dst; edge_src_dst(srcA, dstA, e, src, dst);
    int pos = rowptr[dst] + atomicAdd(&cnt[dst], 1);
    esrc[pos] = src;
    epos[e] = pos;
}

// C[M,N] = A[M,128] * B[128,N], fp32. One row per block, blockDim = N.
__global__ void gemm_row(const float* __restrict__ A, const float* __restrict__ B,
                         float* __restrict__ C, int N) {
    __shared__ float arow[128];
    int m = blockIdx.x;
    int j = threadIdx.x;
    for (int k = j; k < 128; k += blockDim.x) arow[k] = A[(size_t)m * 128 + k];
    __syncthreads();
    float acc = 0.0f;
    #pragma unroll 4
    for (int k = 0; k < 128; ++k) acc += arow[k] * B[(size_t)k * N + j];
    C[(size_t)m * N + j] = acc;
}

// ---------------- Layer 1 (H=8, C=16) ----------------

__global__ void edge_logit1(const int* __restrict__ srcA, const int* __restrict__ dstA,
                            const int* __restrict__ epos,
                            const float* __restrict__ xl, const float* __restrict__ xr,
                            const float* __restrict__ att, float* __restrict__ logit) {
    int idx = blockIdx.x * blockDim.x + threadIdx.x;
    if (idx >= E_TOT * 8) return;
    int e = idx >> 3, hd = idx & 7;
    int src, dst; edge_src_dst(srcA, dstA, e, src, dst);
    int pos = epos[e];
    const float* pl = xl + (size_t)src * 128 + hd * 16;
    const float* pr = xr + (size_t)dst * 128 + hd * 16;
    float acc = 0.0f;
    #pragma unroll
    for (int c = 0; c < 16; ++c) {
        float v = pl[c] + pr[c];
        v = v > 0.0f ? v : NEG_SLOPE * v;
        acc += att[hd * 16 + c] * v;
    }
    logit[(size_t)pos * 8 + hd] = acc;   // CSR-ordered
}

// One node per block (128 threads). Softmax max + exp-sum + weighted aggregation,
// normalize + bias + relu. No atomics.
__global__ void node_fused1(const int* __restrict__ rowptr, const int* __restrict__ esrc,
                            const float* __restrict__ logit, const float* __restrict__ xl,
                            const float* __restrict__ b1, float* __restrict__ hout) {
    int n = blockIdx.x;
    int j = threadIdx.x;          // 0..127, channel
    int hd = j >> 4, l16 = j & 15;
    int beg = rowptr[n], end = rowptr[n + 1];
    // per-head max over the node's edges
    float mx = -FLT_MAX;
    for (int k = beg + l16; k < end; k += 16)
        mx = fmaxf(mx, logit[(size_t)k * 8 + hd]);
    #pragma unroll
    for (int off = 1; off < 16; off <<= 1)
        mx = fmaxf(mx, __shfl_xor(mx, off, 16));
    // single pass: den (redundant per lane-group) + weighted accumulation
    float acc = 0.0f, den = 0.0f;
    for (int k = beg; k < end; ++k) {
        int s = esrc[k];
        float p = __expf(logit[(size_t)k * 8 + hd] - mx);
        den += p;
        acc += p * xl[(size_t)s * 128 + j];
    }
    float v = acc / (den + SM_EPS) + b1[j];
    hout[(size_t)n * 128 + j] = v > 0.0f ? v : 0.0f;
}

// ---------------- Layer 2 (H=1, C=64) ----------------

__global__ void edge_logit2(const int* __restrict__ srcA, const int* __restrict__ dstA,
                            const int* __restrict__ epos,
                            const float* __restrict__ xl, const float* __restrict__ xr,
                            const float* __restrict__ att, float* __restrict__ logit) {
    int e = blockIdx.x * blockDim.x + threadIdx.x;
    if (e >= E_TOT) return;
    int src, dst; edge_src_dst(srcA, dstA, e, src, dst);
    const float* pl = xl + (size_t)src * 64;
    const float* pr = xr + (size_t)dst * 64;
    float acc = 0.0f;
    #pragma unroll 8
    for (int c = 0; c < 64; ++c) {
        float v = pl[c] + pr[c];
        v = v > 0.0f ? v : NEG_SLOPE * v;
        acc += att[c] * v;
    }
    logit[epos[e]] = acc;
}

__global__ void node_fused2(const int* __restrict__ rowptr, const int* __restrict__ esrc,
                            const float* __restrict__ logit, const float* __restrict__ xl,
                            const float* __restrict__ b2v, float* __restrict__ out_emb) {
    int n = blockIdx.x;
    int j = threadIdx.x;          // 0..63
    int beg = rowptr[n], end = rowptr[n + 1];
    float mx = -FLT_MAX;
    for (int k = beg + j; k < end; k += 64) mx = fmaxf(mx, logit[k]);
    #pragma unroll
    for (int off = 1; off < 64; off <<= 1) mx = fmaxf(mx, __shfl_xor(mx, off, 64));
    float acc = 0.0f, den = 0.0f;
    for (int k = beg; k < end; ++k) {
        float p = __expf(logit[k] - mx);
        int s = esrc[k];
        den += p;
        acc += p * xl[(size_t)s * 64 + j];
    }
    out_emb[(size_t)n * 64 + j] = acc / (den + SM_EPS) + b2v[j];
}

// ---------------- Classifier ----------------
__global__ void classifier(const float* __restrict__ emb, const float* __restrict__ Wc1,
                           const float* __restrict__ bc1, const float* __restrict__ Wc2,
                           const float* __restrict__ bc2, float* __restrict__ out_logits) {
    __shared__ float er[64];
    __shared__ float t[128];
    int n = blockIdx.x, j = threadIdx.x;
    if (j < 64) er[j] = emb[(size_t)n * 64 + j];
    __syncthreads();
    float acc = bc1[j];
    #pragma unroll 8
    for (int k = 0; k < 64; ++k) acc += er[k] * Wc1[k * 128 + j];
    t[j] = acc > 0.0f ? acc : 0.0f;
    __syncthreads();
    if (j < 2) {
        float a2 = bc2[j];
        for (int k = 0; k < 128; ++k) a2 += t[k] * Wc2[k * 2 + j];
        out_logits[(size_t)n * 2 + j] = a2;
    }
}

extern "C" void kernel_launch(void* const* d_in, const int* in_sizes, int n_in,
                              void* d_out, int out_size, void* d_ws, size_t ws_size,
                              hipStream_t stream) {
    const float* x    = (const float*)d_in[0];
    const int*   ei   = (const int*)d_in[1];
    const float* Wl1  = (const float*)d_in[3];
    const float* Wr1  = (const float*)d_in[4];
    const float* att1 = (const float*)d_in[5];
    const float* b1   = (const float*)d_in[6];
    const float* Wl2  = (const float*)d_in[7];
    const float* Wr2  = (const float*)d_in[8];
    const float* att2 = (const float*)d_in[9];
    const float* b2   = (const float*)d_in[10];
    const float* Wc1  = (const float*)d_in[15];
    const float* bc1  = (const float*)d_in[16];
    const float* Wc2  = (const float*)d_in[17];
    const float* bc2  = (const float*)d_in[18];

    float* ws = (float*)d_ws;
    // int region
    int* srcA   = (int*)ws;                        // 800000
    int* dstA   = srcA + 800000;                   // 800000
    int* flag   = dstA + 800000;                   // 16 (padded)
    int* deg    = flag + 16;                       // 50000  (deg+cnt zeroed together)
    int* cnt    = deg + 50000;                     // 50000
    int* rowptr = cnt + 50000;                     // 50001 -> pad 50016
    int* esrc   = rowptr + 50016;                  // 850000
    int* epos   = esrc + 850000;                   // 850000
    // float region (word offset 3450032)
    float* xl1    = ws + 3450032;                  // 6.40M  (layer2 xl2 in first 3.2M)
    float* xr1    = ws + 9850032;                  // 6.40M  (layer2 xr2)
    float* hbuf   = ws + 16250032;                 // 6.40M
    float* logit1 = ws + 22650032;                 // 6.80M  (layer2 logit2 in first 0.85M)
    // total 29.45M words ~ 118 MB

    float* out_emb    = (float*)d_out;
    float* out_logits = out_emb + (size_t)N_NODES * 64;

    const int B = 256;
    #define GRID(n) (((n) + B - 1) / B)

    // ---- CSR build ----
    detect_layout<<<1, 256, 0, stream>>>(ei, flag);
    convert_edges<<<GRID(N_EDGES), B, 0, stream>>>(ei, flag, srcA, dstA);
    fill_int<<<GRID(100000), B, 0, stream>>>(deg, 0, 100000);   // deg + cnt
    deg_count<<<GRID(E_TOT), B, 0, stream>>>(srcA, dstA, deg);
    scan_rowptr<<<1, 1024, 0, stream>>>(deg, rowptr);
    scatter_edges<<<GRID(E_TOT), B, 0, stream>>>(srcA, dstA, rowptr, cnt, esrc, epos);

    // ---- layer 1 ----
    gemm_row<<<N_NODES, 128, 0, stream>>>(x, Wl1, xl1, 128);
    gemm_row<<<N_NODES, 128, 0, stream>>>(x, Wr1, xr1, 128);
    edge_logit1<<<GRID(E_TOT * 8), B, 0, stream>>>(srcA, dstA, epos, xl1, xr1, att1, logit1);
    node_fused1<<<N_NODES, 128, 0, stream>>>(rowptr, esrc, logit1, xl1, b1, hbuf);

    // ---- layer 2 ----
    gemm_row<<<N_NODES, 64, 0, stream>>>(hbuf, Wl2, xl1, 64);
    gemm_row<<<N_NODES, 64, 0, stream>>>(hbuf, Wr2, xr1, 64);
    edge_logit2<<<GRID(E_TOT), B, 0, stream>>>(srcA, dstA, epos, xl1, xr1, att2, logit1);
    node_fused2<<<N_NODES, 64, 0, stream>>>(rowptr, esrc, logit1, xl1, b2, out_emb);

    // ---- classifier ----
    classifier<<<N_NODES, 128, 0, stream>>>(out_emb, Wc1, bc1, Wc2, bc2, out_logits);
    #undef GRID
}

// Round 4
// 926.906 us; speedup vs baseline: 10.6395x; 1.2686x over previous
//
#include <hip/hip_runtime.h>
#include <hip/hip_bf16.h>
#include <cfloat>

#define N_NODES 50000
#define N_EDGES 800000
#define E_TOT   850000   /* edges + self-loops */
#define NEG_SLOPE 0.2f
#define SM_EPS 1e-16f

__global__ void fill_int(int* __restrict__ p, int v, int n) {
    int i = blockIdx.x * blockDim.x + threadIdx.x;
    if (i < n) p[i] = v;
}

// Detect edge_index storage: int64 (odd 32-bit words all zero, ids<50000) vs int32.
__global__ void detect_layout(const int* __restrict__ ei, int* __restrict__ flag) {
    __shared__ int any;
    if (threadIdx.x == 0) any = 0;
    __syncthreads();
    int acc = 0;
    for (int i = threadIdx.x; i < 4096; i += blockDim.x) acc |= ei[2 * i + 1];
    if (acc) atomicOr(&any, 1);
    __syncthreads();
    if (threadIdx.x == 0) *flag = any ? 1 : 0;
}

__global__ void convert_edges(const int* __restrict__ ei, const int* __restrict__ flag,
                              int* __restrict__ src, int* __restrict__ dst) {
    int e = blockIdx.x * blockDim.x + threadIdx.x;
    if (e >= N_EDGES) return;
    if (*flag) {           // int32 layout
        src[e] = ei[e];
        dst[e] = ei[N_EDGES + e];
    } else {               // int64 layout: lo words
        src[e] = ei[2 * e];
        dst[e] = ei[2 * N_EDGES + 2 * e];
    }
}

__device__ __forceinline__ void edge_src_dst(const int* __restrict__ srcA, const int* __restrict__ dstA,
                                             int e, int& src, int& dst) {
    if (e < N_EDGES) { src = srcA[e]; dst = dstA[e]; }
    else             { src = e - N_EDGES; dst = src; }
}

__global__ void deg_count(const int* __restrict__ srcA, const int* __restrict__ dstA,
                          int* __restrict__ deg) {
    int e = blockIdx.x * blockDim.x + threadIdx.x;
    if (e >= E_TOT) return;
    int src, dst; edge_src_dst(srcA, dstA, e, src, dst);
    atomicAdd(&deg[dst], 1);
}

// Single-block exclusive scan of deg[N_NODES] -> rowptr[N_NODES+1]. 1024 threads.
__global__ void scan_rowptr(const int* __restrict__ deg, int* __restrict__ rowptr) {
    __shared__ int partial[1024];
    const int CH = (N_NODES + 1023) / 1024;   // 49
    int t = threadIdx.x;
    int base = t * CH;
    int sum = 0;
    for (int i = 0; i < CH; ++i) { int idx = base + i; if (idx < N_NODES) sum += deg[idx]; }
    partial[t] = sum;
    __syncthreads();
    for (int off = 1; off < 1024; off <<= 1) {
        int v = (t >= off) ? partial[t - off] : 0;
        __syncthreads();
        partial[t] += v;
        __syncthreads();
    }
    int run = (t == 0) ? 0 : partial[t - 1];
    for (int i = 0; i < CH; ++i) {
        int idx = base + i;
        if (idx < N_NODES) { rowptr[idx] = run; run += deg[idx]; }
    }
    if (t == 1023) rowptr[N_NODES] = partial[1023];
}

__global__ void scatter_edges(const int* __restrict__ srcA, const int* __restrict__ dstA,
                              const int* __restrict__ rowptr, int* __restrict__ cnt,
                              int* __restrict__ esrc) {
    int e = blockIdx.x * blockDim.x + threadIdx.x;
    if (e >= E_TOT) return;
    int src, dst; edge_src_dst(srcA, dstA, e, src, dst);
    int pos = rowptr[dst] + atomicAdd(&cnt[dst], 1);
    esrc[pos] = src;
}

// C[M,N] = A[M,128] * B[128,N], fp32. One row per block, blockDim = N.
__global__ void gemm_row(const float* __restrict__ A, const float* __restrict__ B,
                         float* __restrict__ C, int N) {
    __shared__ float arow[128];
    int m = blockIdx.x;
    int j = threadIdx.x;
    for (int k = j; k < 128; k += blockDim.x) arow[k] = A[(size_t)m * 128 + k];
    __syncthreads();
    float acc = 0.0f;
    #pragma unroll 4
    for (int k = 0; k < 128; ++k) acc += arow[k] * B[(size_t)k * N + j];
    C[(size_t)m * N + j] = acc;
}

// ---------------- Layer 1 (H=8, C=16) fused: logit + online softmax + agg ----------------
// One node per block, 128 threads (channel j, head j>>4). No atomics, no logit array.
__global__ void node_fused1(const int* __restrict__ rowptr, const int* __restrict__ esrc,
                            const float* __restrict__ xl, const float* __restrict__ xr,
                            const float* __restrict__ att, const float* __restrict__ b1,
                            float* __restrict__ hout) {
    int n = blockIdx.x;
    int j = threadIdx.x;              // 0..127
    int beg = rowptr[n], end = rowptr[n + 1];
    float xr_j  = xr[(size_t)n * 128 + j];
    float att_j = att[j];             // att1 flattened [8*16]
    float m = -FLT_MAX, den = 0.0f, acc = 0.0f;
    int s0 = esrc[beg];
    float xv = xl[(size_t)s0 * 128 + j];
    for (int k = beg; k < end; ++k) {
        float xv_cur = xv;
        if (k + 1 < end) {            // prefetch next row
            int s = esrc[k + 1];
            xv = xl[(size_t)s * 128 + j];
        }
        float v = xv_cur + xr_j;
        v = v > 0.0f ? v : NEG_SLOPE * v;
        v *= att_j;
        #pragma unroll
        for (int off = 1; off < 16; off <<= 1) v += __shfl_xor(v, off, 16);
        float mn = fmaxf(m, v);
        float scale = __expf(m - mn);
        float p = __expf(v - mn);
        den = den * scale + p;
        acc = acc * scale + p * xv_cur;
        m = mn;
    }
    float o = acc / (den + SM_EPS) + b1[j];
    hout[(size_t)n * 128 + j] = o > 0.0f ? o : 0.0f;
}

// ---------------- Layer 2 (H=1, C=64) fused ----------------
// One node per block, 64 threads (one wave).
__global__ void node_fused2(const int* __restrict__ rowptr, const int* __restrict__ esrc,
                            const float* __restrict__ xl, const float* __restrict__ xr,
                            const float* __restrict__ att, const float* __restrict__ b2v,
                            float* __restrict__ out_emb) {
    int n = blockIdx.x;
    int j = threadIdx.x;              // 0..63
    int beg = rowptr[n], end = rowptr[n + 1];
    float xr_j  = xr[(size_t)n * 64 + j];
    float att_j = att[j];
    float m = -FLT_MAX, den = 0.0f, acc = 0.0f;
    int s0 = esrc[beg];
    float xv = xl[(size_t)s0 * 64 + j];
    for (int k = beg; k < end; ++k) {
        float xv_cur = xv;
        if (k + 1 < end) {
            int s = esrc[k + 1];
            xv = xl[(size_t)s * 64 + j];
        }
        float v = xv_cur + xr_j;
        v = v > 0.0f ? v : NEG_SLOPE * v;
        v *= att_j;
        #pragma unroll
        for (int off = 1; off < 64; off <<= 1) v += __shfl_xor(v, off, 64);
        float mn = fmaxf(m, v);
        float scale = __expf(m - mn);
        float p = __expf(v - mn);
        den = den * scale + p;
        acc = acc * scale + p * xv_cur;
        m = mn;
    }
    out_emb[(size_t)n * 64 + j] = acc / (den + SM_EPS) + b2v[j];
}

// ---------------- Classifier ----------------
// logits = relu(emb @ Wc1 + bc1) @ Wc2 + bc2 ;  Wc1 [64,128], Wc2 [128,2]
__global__ void classifier(const float* __restrict__ emb, const float* __restrict__ Wc1,
                           const float* __restrict__ bc1, const float* __restrict__ Wc2,
                           const float* __restrict__ bc2, float* __restrict__ out_logits) {
    __shared__ float er[64];
    __shared__ float t[128];
    int n = blockIdx.x, j = threadIdx.x;
    if (j < 64) er[j] = emb[(size_t)n * 64 + j];
    __syncthreads();
    float acc = bc1[j];
    #pragma unroll 8
    for (int k = 0; k < 64; ++k) acc += er[k] * Wc1[k * 128 + j];
    t[j] = acc > 0.0f ? acc : 0.0f;
    __syncthreads();
    if (j < 2) {
        float a2 = bc2[j];
        for (int k = 0; k < 128; ++k) a2 += t[k] * Wc2[k * 2 + j];
        out_logits[(size_t)n * 2 + j] = a2;
    }
}

extern "C" void kernel_launch(void* const* d_in, const int* in_sizes, int n_in,
                              void* d_out, int out_size, void* d_ws, size_t ws_size,
                              hipStream_t stream) {
    const float* x    = (const float*)d_in[0];
    const int*   ei   = (const int*)d_in[1];
    const float* Wl1  = (const float*)d_in[3];
    const float* Wr1  = (const float*)d_in[4];
    const float* att1 = (const float*)d_in[5];
    const float* b1   = (const float*)d_in[6];
    const float* Wl2  = (const float*)d_in[7];
    const float* Wr2  = (const float*)d_in[8];
    const float* att2 = (const float*)d_in[9];
    const float* b2   = (const float*)d_in[10];
    const float* Wc1  = (const float*)d_in[15];
    const float* bc1  = (const float*)d_in[16];
    const float* Wc2  = (const float*)d_in[17];
    const float* bc2  = (const float*)d_in[18];

    float* ws = (float*)d_ws;
    // int region
    int* srcA   = (int*)ws;                        // 800000
    int* dstA   = srcA + 800000;                   // 800000
    int* flag   = dstA + 800000;                   // 16 (padded)
    int* deg    = flag + 16;                       // 50000  (deg+cnt zeroed together)
    int* cnt    = deg + 50000;                     // 50000
    int* rowptr = cnt + 50000;                     // 50001 -> pad 50016
    int* esrc   = rowptr + 50016;                  // 850000 -> pad to word offset 2600032
    // float region
    float* xl1  = ws + 2600032;                    // 6.40M  (layer2 xl2 in first 3.2M)
    float* xr1  = ws + 9000032;                    // 6.40M  (layer2 xr2)
    float* hbuf = ws + 15400032;                   // 6.40M
    // total ≈ 21.8M words ≈ 87 MB

    float* out_emb    = (float*)d_out;
    float* out_logits = out_emb + (size_t)N_NODES * 64;

    const int B = 256;
    #define GRID(n) (((n) + B - 1) / B)

    // ---- CSR build ----
    detect_layout<<<1, 256, 0, stream>>>(ei, flag);
    convert_edges<<<GRID(N_EDGES), B, 0, stream>>>(ei, flag, srcA, dstA);
    fill_int<<<GRID(100000), B, 0, stream>>>(deg, 0, 100000);   // deg + cnt
    deg_count<<<GRID(E_TOT), B, 0, stream>>>(srcA, dstA, deg);
    scan_rowptr<<<1, 1024, 0, stream>>>(deg, rowptr);
    scatter_edges<<<GRID(E_TOT), B, 0, stream>>>(srcA, dstA, rowptr, cnt, esrc);

    // ---- layer 1 ----
    gemm_row<<<N_NODES, 128, 0, stream>>>(x, Wl1, xl1, 128);
    gemm_row<<<N_NODES, 128, 0, stream>>>(x, Wr1, xr1, 128);
    node_fused1<<<N_NODES, 128, 0, stream>>>(rowptr, esrc, xl1, xr1, att1, b1, hbuf);

    // ---- layer 2 ----
    gemm_row<<<N_NODES, 64, 0, stream>>>(hbuf, Wl2, xl1, 64);
    gemm_row<<<N_NODES, 64, 0, stream>>>(hbuf, Wr2, xr1, 64);
    node_fused2<<<N_NODES, 64, 0, stream>>>(rowptr, esrc, xl1, xr1, att2, b2, out_emb);

    // ---- classifier ----
    classifier<<<N_NODES, 128, 0, stream>>>(out_emb, Wc1, bc1, Wc2, bc2, out_logits);
    #undef GRID
}

// Round 5
// 518.173 us; speedup vs baseline: 19.0320x; 1.7888x over previous
//
#include <hip/hip_runtime.h>
#include <hip/hip_bf16.h>
#include <cfloat>

#define N_NODES 50000
#define N_EDGES 800000
#define E_TOT   850000   /* edges + self-loops */
#define NEG_SLOPE 0.2f
#define SM_EPS 1e-16f
#define SCAN_B 196       /* ceil(50000/256) */

__global__ void fill_int(int* __restrict__ p, int v, int n) {
    int i = blockIdx.x * blockDim.x + threadIdx.x;
    if (i < n) p[i] = v;
}

// Detect edge_index storage: int64 (odd 32-bit words all zero, ids<50000) vs int32.
__global__ void detect_layout(const int* __restrict__ ei, int* __restrict__ flag) {
    __shared__ int any;
    if (threadIdx.x == 0) any = 0;
    __syncthreads();
    int acc = 0;
    for (int i = threadIdx.x; i < 4096; i += blockDim.x) acc |= ei[2 * i + 1];
    if (acc) atomicOr(&any, 1);
    __syncthreads();
    if (threadIdx.x == 0) *flag = any ? 1 : 0;
}

__global__ void convert_edges(const int* __restrict__ ei, const int* __restrict__ flag,
                              int* __restrict__ src, int* __restrict__ dst) {
    int e = blockIdx.x * blockDim.x + threadIdx.x;
    if (e >= N_EDGES) return;
    if (*flag) {           // int32 layout
        src[e] = ei[e];
        dst[e] = ei[N_EDGES + e];
    } else {               // int64 layout: lo words
        src[e] = ei[2 * e];
        dst[e] = ei[2 * N_EDGES + 2 * e];
    }
}

__device__ __forceinline__ void edge_src_dst(const int* __restrict__ srcA, const int* __restrict__ dstA,
                                             int e, int& src, int& dst) {
    if (e < N_EDGES) { src = srcA[e]; dst = dstA[e]; }
    else             { src = e - N_EDGES; dst = src; }
}

__global__ void deg_count(const int* __restrict__ srcA, const int* __restrict__ dstA,
                          int* __restrict__ deg) {
    int e = blockIdx.x * blockDim.x + threadIdx.x;
    if (e >= E_TOT) return;
    int src, dst; edge_src_dst(srcA, dstA, e, src, dst);
    atomicAdd(&deg[dst], 1);
}

// ---- blocked exclusive scan: local scan -> block-sum scan -> add offsets ----
__global__ void scan_local(const int* __restrict__ deg, int* __restrict__ rowptr,
                           int* __restrict__ bsum) {
    __shared__ int sh[256];
    int b = blockIdx.x, t = threadIdx.x, i = b * 256 + t;
    int v = (i < N_NODES) ? deg[i] : 0;
    sh[t] = v;
    __syncthreads();
    int val = v;
    for (int off = 1; off < 256; off <<= 1) {
        int add = (t >= off) ? sh[t - off] : 0;
        __syncthreads();
        val += add; sh[t] = val;
        __syncthreads();
    }
    if (i < N_NODES) rowptr[i] = val - v;   // exclusive within block
    if (t == 255) bsum[b] = val;
}

__global__ void scan_bsum(int* __restrict__ bsum) {
    __shared__ int sh[256];
    int t = threadIdx.x;
    int v = (t < SCAN_B) ? bsum[t] : 0;
    sh[t] = v;
    __syncthreads();
    int val = v;
    for (int off = 1; off < 256; off <<= 1) {
        int add = (t >= off) ? sh[t - off] : 0;
        __syncthreads();
        val += add; sh[t] = val;
        __syncthreads();
    }
    if (t < SCAN_B) bsum[t] = val - v;      // exclusive block offsets
}

__global__ void scan_add(int* __restrict__ rowptr, const int* __restrict__ bsum) {
    int b = blockIdx.x, t = threadIdx.x, i = b * 256 + t;
    if (i < N_NODES) rowptr[i] += bsum[b];
    if (i == 0) rowptr[N_NODES] = E_TOT;
}

__global__ void scatter_edges(const int* __restrict__ srcA, const int* __restrict__ dstA,
                              const int* __restrict__ rowptr, int* __restrict__ cnt,
                              int* __restrict__ esrc) {
    int e = blockIdx.x * blockDim.x + threadIdx.x;
    if (e >= E_TOT) return;
    int src, dst; edge_src_dst(srcA, dstA, e, src, dst);
    int pos = rowptr[dst] + atomicAdd(&cnt[dst], 1);
    esrc[pos] = src;
}

// ---------------- GEMM pair: C0 = A@B0, C1 = A@B1 ; A[M,128], B[128,N] ----------------
// 32 rows/block. A staged transposed in LDS (pad 36 keeps 16B alignment, spreads banks).
// Thread tile: 16 rows x 4 cols. Block threads = 4*(N/4).
template<int N>
__global__ __launch_bounds__(4*(N/4))
void gemm_pair(const float* __restrict__ A, const float* __restrict__ B0,
               const float* __restrict__ B1, float* __restrict__ C0,
               float* __restrict__ C1, int M) {
    const int JQ = N / 4;
    const int NT = 4 * JQ;
    __shared__ float aT[128][36];
    int t = threadIdx.x;
    int jq    = t & (JQ - 1);
    int rh    = (t / JQ) & 1;
    int which = t / (2 * JQ);
    const float* B = which ? B1 : B0;
    float*       C = which ? C1 : C0;
    int row0 = blockIdx.x * 32;
    for (int i = t; i < 32 * 128; i += NT) {
        int r = i >> 7, kk = i & 127;
        int row = row0 + r;
        aT[kk][r] = (row < M) ? A[(size_t)row * 128 + kk] : 0.0f;
    }
    __syncthreads();
    float acc[16][4];
    #pragma unroll
    for (int r = 0; r < 16; ++r)
        #pragma unroll
        for (int c = 0; c < 4; ++c) acc[r][c] = 0.0f;
    const float* Bp = B + jq * 4;
    const int rbase = rh * 16;
    for (int k = 0; k < 128; ++k) {
        float4 b4 = *(const float4*)(Bp + (size_t)k * N);
        float av[16];
        const float* ar = &aT[k][rbase];
        *(float4*)&av[0]  = *(const float4*)(ar);
        *(float4*)&av[4]  = *(const float4*)(ar + 4);
        *(float4*)&av[8]  = *(const float4*)(ar + 8);
        *(float4*)&av[12] = *(const float4*)(ar + 12);
        #pragma unroll
        for (int r = 0; r < 16; ++r) {
            acc[r][0] += av[r] * b4.x;
            acc[r][1] += av[r] * b4.y;
            acc[r][2] += av[r] * b4.z;
            acc[r][3] += av[r] * b4.w;
        }
    }
    #pragma unroll
    for (int r = 0; r < 16; ++r) {
        int row = row0 + rbase + r;
        if (row < M) {
            float4 o; o.x = acc[r][0]; o.y = acc[r][1]; o.z = acc[r][2]; o.w = acc[r][3];
            *(float4*)(C + (size_t)row * N + jq * 4) = o;
        }
    }
}

// ---------------- Layer 1 (H=8, C=16) fused, 4-way edge ILP ----------------
__global__ void node_fused1(const int* __restrict__ rowptr, const int* __restrict__ esrc,
                            const float* __restrict__ xl, const float* __restrict__ xr,
                            const float* __restrict__ att, const float* __restrict__ b1,
                            float* __restrict__ hout) {
    int n = blockIdx.x;
    int j = threadIdx.x;              // 0..127
    int beg = rowptr[n], end = rowptr[n + 1];
    float xr_j  = xr[(size_t)n * 128 + j];
    float att_j = att[j];
    float M[4], D[4], A[4];
    #pragma unroll
    for (int u = 0; u < 4; ++u) { M[u] = -FLT_MAX; D[u] = 0.0f; A[u] = 0.0f; }
    int k = beg;
    for (; k + 4 <= end; k += 4) {
        int s[4]; float xv[4];
        #pragma unroll
        for (int u = 0; u < 4; ++u) s[u] = esrc[k + u];
        #pragma unroll
        for (int u = 0; u < 4; ++u) xv[u] = xl[(size_t)s[u] * 128 + j];
        #pragma unroll
        for (int u = 0; u < 4; ++u) {
            float v = xv[u] + xr_j;
            v = v > 0.0f ? v : NEG_SLOPE * v;
            v *= att_j;
            #pragma unroll
            for (int off = 1; off < 16; off <<= 1) v += __shfl_xor(v, off, 16);
            float mn = fmaxf(M[u], v);
            float sc = __expf(M[u] - mn);
            float p  = __expf(v - mn);
            D[u] = D[u] * sc + p;
            A[u] = A[u] * sc + p * xv[u];
            M[u] = mn;
        }
    }
    for (; k < end; ++k) {
        int s = esrc[k];
        float xv = xl[(size_t)s * 128 + j];
        float v = xv + xr_j;
        v = v > 0.0f ? v : NEG_SLOPE * v;
        v *= att_j;
        #pragma unroll
        for (int off = 1; off < 16; off <<= 1) v += __shfl_xor(v, off, 16);
        float mn = fmaxf(M[0], v);
        float sc = __expf(M[0] - mn);
        float p  = __expf(v - mn);
        D[0] = D[0] * sc + p;
        A[0] = A[0] * sc + p * xv;
        M[0] = mn;
    }
    float mAll = fmaxf(fmaxf(M[0], M[1]), fmaxf(M[2], M[3]));
    float den = 0.0f, acc = 0.0f;
    #pragma unroll
    for (int u = 0; u < 4; ++u) {
        float sc = __expf(M[u] - mAll);
        den += D[u] * sc;
        acc += A[u] * sc;
    }
    float o = acc / (den + SM_EPS) + b1[j];
    hout[(size_t)n * 128 + j] = o > 0.0f ? o : 0.0f;
}

// ---------------- Layer 2 (H=1, C=64) fused, 4-way edge ILP ----------------
__global__ void node_fused2(const int* __restrict__ rowptr, const int* __restrict__ esrc,
                            const float* __restrict__ xl, const float* __restrict__ xr,
                            const float* __restrict__ att, const float* __restrict__ b2v,
                            float* __restrict__ out_emb) {
    int n = blockIdx.x;
    int j = threadIdx.x;              // 0..63
    int beg = rowptr[n], end = rowptr[n + 1];
    float xr_j  = xr[(size_t)n * 64 + j];
    float att_j = att[j];
    float M[4], D[4], A[4];
    #pragma unroll
    for (int u = 0; u < 4; ++u) { M[u] = -FLT_MAX; D[u] = 0.0f; A[u] = 0.0f; }
    int k = beg;
    for (; k + 4 <= end; k += 4) {
        int s[4]; float xv[4];
        #pragma unroll
        for (int u = 0; u < 4; ++u) s[u] = esrc[k + u];
        #pragma unroll
        for (int u = 0; u < 4; ++u) xv[u] = xl[(size_t)s[u] * 64 + j];
        #pragma unroll
        for (int u = 0; u < 4; ++u) {
            float v = xv[u] + xr_j;
            v = v > 0.0f ? v : NEG_SLOPE * v;
            v *= att_j;
            #pragma unroll
            for (int off = 1; off < 64; off <<= 1) v += __shfl_xor(v, off, 64);
            float mn = fmaxf(M[u], v);
            float sc = __expf(M[u] - mn);
            float p  = __expf(v - mn);
            D[u] = D[u] * sc + p;
            A[u] = A[u] * sc + p * xv[u];
            M[u] = mn;
        }
    }
    for (; k < end; ++k) {
        int s = esrc[k];
        float xv = xl[(size_t)s * 64 + j];
        float v = xv + xr_j;
        v = v > 0.0f ? v : NEG_SLOPE * v;
        v *= att_j;
        #pragma unroll
        for (int off = 1; off < 64; off <<= 1) v += __shfl_xor(v, off, 64);
        float mn = fmaxf(M[0], v);
        float sc = __expf(M[0] - mn);
        float p  = __expf(v - mn);
        D[0] = D[0] * sc + p;
        A[0] = A[0] * sc + p * xv;
        M[0] = mn;
    }
    float mAll = fmaxf(fmaxf(M[0], M[1]), fmaxf(M[2], M[3]));
    float den = 0.0f, acc = 0.0f;
    #pragma unroll
    for (int u = 0; u < 4; ++u) {
        float sc = __expf(M[u] - mAll);
        den += D[u] * sc;
        acc += A[u] * sc;
    }
    out_emb[(size_t)n * 64 + j] = acc / (den + SM_EPS) + b2v[j];
}

// ---------------- Classifier ----------------
// logits = relu(emb @ Wc1 + bc1) @ Wc2 + bc2 ;  Wc1 [64,128], Wc2 [128,2]
__global__ void classifier(const float* __restrict__ emb, const float* __restrict__ Wc1,
                           const float* __restrict__ bc1, const float* __restrict__ Wc2,
                           const float* __restrict__ bc2, float* __restrict__ out_logits) {
    __shared__ float red[2][2];
    int n = blockIdx.x, j = threadIdx.x;   // 128 threads
    const float* er = emb + (size_t)n * 64;
    float acc = bc1[j];
    #pragma unroll 8
    for (int k = 0; k < 64; ++k) acc += er[k] * Wc1[k * 128 + j];   // er[k] wave-uniform
    float tj = fmaxf(acc, 0.0f);
    float v0 = tj * Wc2[j * 2];
    float v1 = tj * Wc2[j * 2 + 1];
    #pragma unroll
    for (int off = 32; off; off >>= 1) {
        v0 += __shfl_down(v0, off, 64);
        v1 += __shfl_down(v1, off, 64);
    }
    if ((j & 63) == 0) { red[j >> 6][0] = v0; red[j >> 6][1] = v1; }
    __syncthreads();
    if (j == 0) {
        out_logits[(size_t)n * 2 + 0] = red[0][0] + red[1][0] + bc2[0];
        out_logits[(size_t)n * 2 + 1] = red[0][1] + red[1][1] + bc2[1];
    }
}

extern "C" void kernel_launch(void* const* d_in, const int* in_sizes, int n_in,
                              void* d_out, int out_size, void* d_ws, size_t ws_size,
                              hipStream_t stream) {
    const float* x    = (const float*)d_in[0];
    const int*   ei   = (const int*)d_in[1];
    const float* Wl1  = (const float*)d_in[3];
    const float* Wr1  = (const float*)d_in[4];
    const float* att1 = (const float*)d_in[5];
    const float* b1   = (const float*)d_in[6];
    const float* Wl2  = (const float*)d_in[7];
    const float* Wr2  = (const float*)d_in[8];
    const float* att2 = (const float*)d_in[9];
    const float* b2   = (const float*)d_in[10];
    const float* Wc1  = (const float*)d_in[15];
    const float* bc1  = (const float*)d_in[16];
    const float* Wc2  = (const float*)d_in[17];
    const float* bc2  = (const float*)d_in[18];

    float* ws = (float*)d_ws;
    // int region
    int* srcA   = (int*)ws;                        // 800000
    int* dstA   = srcA + 800000;                   // 800000
    int* flag   = dstA + 800000;                   // 16
    int* deg    = flag + 16;                       // 50000 (deg+cnt zeroed together)
    int* cnt    = deg + 50000;                     // 50000
    int* rowptr = cnt + 50000;                     // 50001 -> pad 50016
    int* esrc   = rowptr + 50016;                  // 850000
    int* bsum   = esrc + 850000;                   // 196 -> floats at 2600256
    // float region
    float* xl1  = ws + 2600256;                    // 6.40M (layer2 xl2 in first 3.2M)
    float* xr1  = ws + 9000256;                    // 6.40M (layer2 xr2)
    float* hbuf = ws + 15400256;                   // 6.40M
    // total ≈ 21.8M words ≈ 87 MB

    float* out_emb    = (float*)d_out;
    float* out_logits = out_emb + (size_t)N_NODES * 64;

    const int B = 256;
    #define GRID(n) (((n) + B - 1) / B)

    // ---- CSR build ----
    detect_layout<<<1, 256, 0, stream>>>(ei, flag);
    convert_edges<<<GRID(N_EDGES), B, 0, stream>>>(ei, flag, srcA, dstA);
    fill_int<<<GRID(100000), B, 0, stream>>>(deg, 0, 100000);   // deg + cnt
    deg_count<<<GRID(E_TOT), B, 0, stream>>>(srcA, dstA, deg);
    scan_local<<<SCAN_B, 256, 0, stream>>>(deg, rowptr, bsum);
    scan_bsum<<<1, 256, 0, stream>>>(bsum);
    scan_add<<<SCAN_B, 256, 0, stream>>>(rowptr, bsum);
    scatter_edges<<<GRID(E_TOT), B, 0, stream>>>(srcA, dstA, rowptr, cnt, esrc);

    // ---- layer 1 ----
    gemm_pair<128><<<1563, 128, 0, stream>>>(x, Wl1, Wr1, xl1, xr1, N_NODES);
    node_fused1<<<N_NODES, 128, 0, stream>>>(rowptr, esrc, xl1, xr1, att1, b1, hbuf);

    // ---- layer 2 ----
    gemm_pair<64><<<1563, 64, 0, stream>>>(hbuf, Wl2, Wr2, xl1, xr1, N_NODES);
    node_fused2<<<N_NODES, 64, 0, stream>>>(rowptr, esrc, xl1, xr1, att2, b2, out_emb);

    // ---- classifier ----
    classifier<<<N_NODES, 128, 0, stream>>>(out_emb, Wc1, bc1, Wc2, bc2, out_logits);
    #undef GRID
}

// Round 6
// 497.133 us; speedup vs baseline: 19.8375x; 1.0423x over previous
//
#include <hip/hip_runtime.h>
#include <hip/hip_bf16.h>
#include <cfloat>

#define N_NODES 50000
#define N_EDGES 800000
#define E_TOT   850000   /* edges + self-loops */
#define NEG_SLOPE 0.2f
#define SM_EPS 1e-16f
#define SCAN_B 196       /* ceil(50000/256) */

// Detect edge_index storage: int64 (odd 32-bit words all zero, ids<50000) vs int32.
__global__ void detect_layout(const int* __restrict__ ei, int* __restrict__ flag) {
    __shared__ int any;
    if (threadIdx.x == 0) any = 0;
    __syncthreads();
    int acc = 0;
    for (int i = threadIdx.x; i < 4096; i += blockDim.x) acc |= ei[2 * i + 1];
    if (acc) atomicOr(&any, 1);
    __syncthreads();
    if (threadIdx.x == 0) *flag = any ? 1 : 0;
}

__global__ void count_deg(const int* __restrict__ ei, const int* __restrict__ flag,
                          int* __restrict__ deg) {
    int e = blockIdx.x * blockDim.x + threadIdx.x;
    if (e >= N_EDGES) return;
    int dst = *flag ? ei[N_EDGES + e] : ei[2 * N_EDGES + 2 * e];
    atomicAdd(&deg[dst], 1);
}

// ---- blocked exclusive scan; +1 per node folds in the self-loop ----
__global__ void scan_local(const int* __restrict__ deg, int* __restrict__ rowptr,
                           int* __restrict__ bsum) {
    __shared__ int sh[256];
    int b = blockIdx.x, t = threadIdx.x, i = b * 256 + t;
    int v = (i < N_NODES) ? deg[i] + 1 : 0;
    sh[t] = v;
    __syncthreads();
    int val = v;
    for (int off = 1; off < 256; off <<= 1) {
        int add = (t >= off) ? sh[t - off] : 0;
        __syncthreads();
        val += add; sh[t] = val;
        __syncthreads();
    }
    if (i < N_NODES) rowptr[i] = val - v;   // exclusive within block
    if (t == 255) bsum[b] = val;
}

__global__ void scan_bsum(int* __restrict__ bsum) {
    __shared__ int sh[256];
    int t = threadIdx.x;
    int v = (t < SCAN_B) ? bsum[t] : 0;
    sh[t] = v;
    __syncthreads();
    int val = v;
    for (int off = 1; off < 256; off <<= 1) {
        int add = (t >= off) ? sh[t - off] : 0;
        __syncthreads();
        val += add; sh[t] = val;
        __syncthreads();
    }
    if (t < SCAN_B) bsum[t] = val - v;      // exclusive block offsets
}

// add block offsets; write self-loop into slot 0 of each node's segment
__global__ void scan_add(int* __restrict__ rowptr, const int* __restrict__ bsum,
                         int* __restrict__ esrc) {
    int b = blockIdx.x, t = threadIdx.x, i = b * 256 + t;
    if (i < N_NODES) {
        int rp = rowptr[i] + bsum[b];
        rowptr[i] = rp;
        esrc[rp] = i;       // self-loop first
    }
    if (i == 0) rowptr[N_NODES] = E_TOT;
}

__global__ void scatter_edges(const int* __restrict__ ei, const int* __restrict__ flag,
                              const int* __restrict__ rowptr, int* __restrict__ cnt,
                              int* __restrict__ esrc) {
    int e = blockIdx.x * blockDim.x + threadIdx.x;
    if (e >= N_EDGES) return;
    int src, dst;
    if (*flag) { src = ei[e];     dst = ei[N_EDGES + e]; }
    else       { src = ei[2 * e]; dst = ei[2 * N_EDGES + 2 * e]; }
    int pos = rowptr[dst] + 1 + atomicAdd(&cnt[dst], 1);
    esrc[pos] = src;
}

// ---------------- GEMM pair: C0 = A@B0, C1 = A@B1 ; A[M,128], B[128,N] ----------------
template<int N>
__global__ __launch_bounds__(4*(N/4))
void gemm_pair(const float* __restrict__ A, const float* __restrict__ B0,
               const float* __restrict__ B1, float* __restrict__ C0,
               float* __restrict__ C1, int M) {
    const int JQ = N / 4;
    const int NT = 4 * JQ;
    __shared__ float aT[128][36];
    int t = threadIdx.x;
    int jq    = t & (JQ - 1);
    int rh    = (t / JQ) & 1;
    int which = t / (2 * JQ);
    const float* B = which ? B1 : B0;
    float*       C = which ? C1 : C0;
    int row0 = blockIdx.x * 32;
    for (int i = t; i < 32 * 128; i += NT) {
        int r = i >> 7, kk = i & 127;
        int row = row0 + r;
        aT[kk][r] = (row < M) ? A[(size_t)row * 128 + kk] : 0.0f;
    }
    __syncthreads();
    float acc[16][4];
    #pragma unroll
    for (int r = 0; r < 16; ++r)
        #pragma unroll
        for (int c = 0; c < 4; ++c) acc[r][c] = 0.0f;
    const float* Bp = B + jq * 4;
    const int rbase = rh * 16;
    for (int k = 0; k < 128; ++k) {
        float4 b4 = *(const float4*)(Bp + (size_t)k * N);
        float av[16];
        const float* ar = &aT[k][rbase];
        *(float4*)&av[0]  = *(const float4*)(ar);
        *(float4*)&av[4]  = *(const float4*)(ar + 4);
        *(float4*)&av[8]  = *(const float4*)(ar + 8);
        *(float4*)&av[12] = *(const float4*)(ar + 12);
        #pragma unroll
        for (int r = 0; r < 16; ++r) {
            acc[r][0] += av[r] * b4.x;
            acc[r][1] += av[r] * b4.y;
            acc[r][2] += av[r] * b4.z;
            acc[r][3] += av[r] * b4.w;
        }
    }
    #pragma unroll
    for (int r = 0; r < 16; ++r) {
        int row = row0 + rbase + r;
        if (row < M) {
            float4 o; o.x = acc[r][0]; o.y = acc[r][1]; o.z = acc[r][2]; o.w = acc[r][3];
            *(float4*)(C + (size_t)row * N + jq * 4) = o;
        }
    }
}

// ---------------- Layer 1 (H=8, C=16): logits + softmax (no max-sub) + agg ----------------
__global__ void node_fused1(const int* __restrict__ rowptr, const int* __restrict__ esrc,
                            const float* __restrict__ xl, const float* __restrict__ xr,
                            const float* __restrict__ att, const float* __restrict__ b1,
                            float* __restrict__ hout) {
    int n = blockIdx.x;
    int j = threadIdx.x;              // 0..127  (head = j>>4)
    int beg = rowptr[n], end = rowptr[n + 1];
    float xr_j  = xr[(size_t)n * 128 + j];
    float att_j = att[j];
    float D[4] = {0,0,0,0}, A[4] = {0,0,0,0};
    int k = beg;
    for (; k + 4 <= end; k += 4) {
        int s[4]; float xv[4];
        #pragma unroll
        for (int u = 0; u < 4; ++u) s[u] = esrc[k + u];
        #pragma unroll
        for (int u = 0; u < 4; ++u) xv[u] = xl[(size_t)s[u] * 128 + j];
        #pragma unroll
        for (int u = 0; u < 4; ++u) {
            float v = xv[u] + xr_j;
            v = v > 0.0f ? v : NEG_SLOPE * v;
            v *= att_j;
            #pragma unroll
            for (int off = 1; off < 16; off <<= 1) v += __shfl_xor(v, off, 16);
            float p = __expf(v);
            D[u] += p;
            A[u] += p * xv[u];
        }
    }
    for (; k < end; ++k) {
        int s = esrc[k];
        float xv = xl[(size_t)s * 128 + j];
        float v = xv + xr_j;
        v = v > 0.0f ? v : NEG_SLOPE * v;
        v *= att_j;
        #pragma unroll
        for (int off = 1; off < 16; off <<= 1) v += __shfl_xor(v, off, 16);
        float p = __expf(v);
        D[0] += p;
        A[0] += p * xv;
    }
    float den = (D[0] + D[1]) + (D[2] + D[3]);
    float acc = (A[0] + A[1]) + (A[2] + A[3]);
    float o = acc / (den + SM_EPS) + b1[j];
    hout[(size_t)n * 128 + j] = o > 0.0f ? o : 0.0f;
}

// ---------------- Layer 2 (H=1, C=64) + fused classifier ----------------
__global__ void node_fused2(const int* __restrict__ rowptr, const int* __restrict__ esrc,
                            const float* __restrict__ xl, const float* __restrict__ xr,
                            const float* __restrict__ att, const float* __restrict__ b2v,
                            const float* __restrict__ Wc1, const float* __restrict__ bc1,
                            const float* __restrict__ Wc2, const float* __restrict__ bc2,
                            float* __restrict__ out_emb, float* __restrict__ out_logits) {
    int n = blockIdx.x;
    int j = threadIdx.x;              // 0..63 (one wave)
    int beg = rowptr[n], end = rowptr[n + 1];
    float xr_j  = xr[(size_t)n * 64 + j];
    float att_j = att[j];
    float D[4] = {0,0,0,0}, A[4] = {0,0,0,0};
    int k = beg;
    for (; k + 4 <= end; k += 4) {
        int s[4]; float xv[4];
        #pragma unroll
        for (int u = 0; u < 4; ++u) s[u] = esrc[k + u];
        #pragma unroll
        for (int u = 0; u < 4; ++u) xv[u] = xl[(size_t)s[u] * 64 + j];
        #pragma unroll
        for (int u = 0; u < 4; ++u) {
            float v = xv[u] + xr_j;
            v = v > 0.0f ? v : NEG_SLOPE * v;
            v *= att_j;
            #pragma unroll
            for (int off = 1; off < 64; off <<= 1) v += __shfl_xor(v, off, 64);
            float p = __expf(v);
            D[u] += p;
            A[u] += p * xv[u];
        }
    }
    for (; k < end; ++k) {
        int s = esrc[k];
        float xv = xl[(size_t)s * 64 + j];
        float v = xv + xr_j;
        v = v > 0.0f ? v : NEG_SLOPE * v;
        v *= att_j;
        #pragma unroll
        for (int off = 1; off < 64; off <<= 1) v += __shfl_xor(v, off, 64);
        float p = __expf(v);
        D[0] += p;
        A[0] += p * xv;
    }
    float den = (D[0] + D[1]) + (D[2] + D[3]);
    float acc = (A[0] + A[1]) + (A[2] + A[3]);
    float emb = acc / (den + SM_EPS) + b2v[j];
    out_emb[(size_t)n * 64 + j] = emb;

    // classifier: t = relu(emb @ Wc1 + bc1) [128]; logits = t @ Wc2 + bc2 [2]
    float t0 = bc1[j], t1 = bc1[j + 64];
    for (int kk = 0; kk < 64; ++kk) {
        float b = __shfl(emb, kk, 64);
        t0 += b * Wc1[kk * 128 + j];
        t1 += b * Wc1[kk * 128 + 64 + j];
    }
    t0 = fmaxf(t0, 0.0f);
    t1 = fmaxf(t1, 0.0f);
    float v0 = t0 * Wc2[2 * j]     + t1 * Wc2[2 * (j + 64)];
    float v1 = t0 * Wc2[2 * j + 1] + t1 * Wc2[2 * (j + 64) + 1];
    #pragma unroll
    for (int off = 1; off < 64; off <<= 1) {
        v0 += __shfl_xor(v0, off, 64);
        v1 += __shfl_xor(v1, off, 64);
    }
    if (j == 0) {
        out_logits[(size_t)n * 2 + 0] = v0 + bc2[0];
        out_logits[(size_t)n * 2 + 1] = v1 + bc2[1];
    }
}

extern "C" void kernel_launch(void* const* d_in, const int* in_sizes, int n_in,
                              void* d_out, int out_size, void* d_ws, size_t ws_size,
                              hipStream_t stream) {
    const float* x    = (const float*)d_in[0];
    const int*   ei   = (const int*)d_in[1];
    const float* Wl1  = (const float*)d_in[3];
    const float* Wr1  = (const float*)d_in[4];
    const float* att1 = (const float*)d_in[5];
    const float* b1   = (const float*)d_in[6];
    const float* Wl2  = (const float*)d_in[7];
    const float* Wr2  = (const float*)d_in[8];
    const float* att2 = (const float*)d_in[9];
    const float* b2   = (const float*)d_in[10];
    const float* Wc1  = (const float*)d_in[15];
    const float* bc1  = (const float*)d_in[16];
    const float* Wc2  = (const float*)d_in[17];
    const float* bc2  = (const float*)d_in[18];

    float* ws = (float*)d_ws;
    // int region
    int* flag   = (int*)ws;                        // 16
    int* deg    = flag + 16;                       // 50000   (deg+cnt zeroed by one memset)
    int* cnt    = deg + 50000;                     // 50000
    int* rowptr = cnt + 50000;                     // 50001 -> pad 50016
    int* esrc   = rowptr + 50016;                  // 850000
    int* bsum   = esrc + 850000;                   // 256
    // float region (16B-aligned word offsets)
    float* xl1  = ws + 1000448;                    // 6.40M (layer2 xl2 in first 3.2M)
    float* xr1  = ws + 7400448;                    // 6.40M (layer2 xr2)
    float* hbuf = ws + 13800448;                   // 6.40M
    // total ≈ 20.2M words ≈ 81 MB

    float* out_emb    = (float*)d_out;
    float* out_logits = out_emb + (size_t)N_NODES * 64;

    const int B = 256;
    #define GRID(n) (((n) + B - 1) / B)

    // ---- CSR build ----
    detect_layout<<<1, 256, 0, stream>>>(ei, flag);
    hipMemsetAsync(deg, 0, 2 * 50000 * sizeof(int), stream);
    count_deg<<<GRID(N_EDGES), B, 0, stream>>>(ei, flag, deg);
    scan_local<<<SCAN_B, 256, 0, stream>>>(deg, rowptr, bsum);
    scan_bsum<<<1, 256, 0, stream>>>(bsum);
    scan_add<<<SCAN_B, 256, 0, stream>>>(rowptr, bsum, esrc);
    scatter_edges<<<GRID(N_EDGES), B, 0, stream>>>(ei, flag, rowptr, cnt, esrc);

    // ---- layer 1 ----
    gemm_pair<128><<<1563, 128, 0, stream>>>(x, Wl1, Wr1, xl1, xr1, N_NODES);
    node_fused1<<<N_NODES, 128, 0, stream>>>(rowptr, esrc, xl1, xr1, att1, b1, hbuf);

    // ---- layer 2 + classifier ----
    gemm_pair<64><<<1563, 64, 0, stream>>>(hbuf, Wl2, Wr2, xl1, xr1, N_NODES);
    node_fused2<<<N_NODES, 64, 0, stream>>>(rowptr, esrc, xl1, xr1, att2, b2,
                                            Wc1, bc1, Wc2, bc2, out_emb, out_logits);
    #undef GRID
}

// Round 7
// 468.790 us; speedup vs baseline: 21.0368x; 1.0605x over previous
//
#include <hip/hip_runtime.h>
#include <hip/hip_bf16.h>
#include <cfloat>

#define N_NODES 50000
#define N_EDGES 800000
#define E_TOT   850000   /* edges + self-loops */
#define NEG_SLOPE 0.2f
#define SM_EPS 1e-16f
#define SCAN_B 196       /* ceil(50000/256) */

__device__ __forceinline__ float lrelu(float v) { return v > 0.0f ? v : NEG_SLOPE * v; }

// Detect edge_index storage: int64 (odd 32-bit words all zero, ids<50000) vs int32.
__global__ void detect_layout(const int* __restrict__ ei, int* __restrict__ flag) {
    __shared__ int any;
    if (threadIdx.x == 0) any = 0;
    __syncthreads();
    int acc = 0;
    for (int i = threadIdx.x; i < 4096; i += blockDim.x) acc |= ei[2 * i + 1];
    if (acc) atomicOr(&any, 1);
    __syncthreads();
    if (threadIdx.x == 0) *flag = any ? 1 : 0;
}

__global__ void count_deg(const int* __restrict__ ei, const int* __restrict__ flag,
                          int* __restrict__ deg) {
    int e = blockIdx.x * blockDim.x + threadIdx.x;
    if (e >= N_EDGES) return;
    int dst = *flag ? ei[N_EDGES + e] : ei[2 * N_EDGES + 2 * e];
    atomicAdd(&deg[dst], 1);
}

// ---- blocked exclusive scan; +1 per node folds in the self-loop ----
__global__ void scan_local(const int* __restrict__ deg, int* __restrict__ rowptr,
                           int* __restrict__ bsum) {
    __shared__ int sh[256];
    int b = blockIdx.x, t = threadIdx.x, i = b * 256 + t;
    int v = (i < N_NODES) ? deg[i] + 1 : 0;
    sh[t] = v;
    __syncthreads();
    int val = v;
    for (int off = 1; off < 256; off <<= 1) {
        int add = (t >= off) ? sh[t - off] : 0;
        __syncthreads();
        val += add; sh[t] = val;
        __syncthreads();
    }
    if (i < N_NODES) rowptr[i] = val - v;   // exclusive within block
    if (t == 255) bsum[b] = val;
}

__global__ void scan_bsum(int* __restrict__ bsum) {
    __shared__ int sh[256];
    int t = threadIdx.x;
    int v = (t < SCAN_B) ? bsum[t] : 0;
    sh[t] = v;
    __syncthreads();
    int val = v;
    for (int off = 1; off < 256; off <<= 1) {
        int add = (t >= off) ? sh[t - off] : 0;
        __syncthreads();
        val += add; sh[t] = val;
        __syncthreads();
    }
    if (t < SCAN_B) bsum[t] = val - v;      // exclusive block offsets
}

// add block offsets; write self-loop into slot 0 of each node's segment
__global__ void scan_add(int* __restrict__ rowptr, const int* __restrict__ bsum,
                         int* __restrict__ esrc) {
    int b = blockIdx.x, t = threadIdx.x, i = b * 256 + t;
    if (i < N_NODES) {
        int rp = rowptr[i] + bsum[b];
        rowptr[i] = rp;
        esrc[rp] = i;       // self-loop first
    }
    if (i == 0) rowptr[N_NODES] = E_TOT;
}

__global__ void scatter_edges(const int* __restrict__ ei, const int* __restrict__ flag,
                              const int* __restrict__ rowptr, int* __restrict__ cnt,
                              int* __restrict__ esrc) {
    int e = blockIdx.x * blockDim.x + threadIdx.x;
    if (e >= N_EDGES) return;
    int src, dst;
    if (*flag) { src = ei[e];     dst = ei[N_EDGES + e]; }
    else       { src = ei[2 * e]; dst = ei[2 * N_EDGES + 2 * e]; }
    int pos = rowptr[dst] + 1 + atomicAdd(&cnt[dst], 1);
    esrc[pos] = src;
}

// ---------------- GEMM pair: C0 = A@B0, C1 = A@B1 ; A[M,128], B[128,N] ----------------
template<int N>
__global__ __launch_bounds__(4*(N/4))
void gemm_pair(const float* __restrict__ A, const float* __restrict__ B0,
               const float* __restrict__ B1, float* __restrict__ C0,
               float* __restrict__ C1, int M) {
    const int JQ = N / 4;
    const int NT = 4 * JQ;
    __shared__ float aT[128][36];
    int t = threadIdx.x;
    int jq    = t & (JQ - 1);
    int rh    = (t / JQ) & 1;
    int which = t / (2 * JQ);
    const float* B = which ? B1 : B0;
    float*       C = which ? C1 : C0;
    int row0 = blockIdx.x * 32;
    for (int i = t; i < 32 * 128; i += NT) {
        int r = i >> 7, kk = i & 127;
        int row = row0 + r;
        aT[kk][r] = (row < M) ? A[(size_t)row * 128 + kk] : 0.0f;
    }
    __syncthreads();
    float acc[16][4];
    #pragma unroll
    for (int r = 0; r < 16; ++r)
        #pragma unroll
        for (int c = 0; c < 4; ++c) acc[r][c] = 0.0f;
    const float* Bp = B + jq * 4;
    const int rbase = rh * 16;
    for (int k = 0; k < 128; ++k) {
        float4 b4 = *(const float4*)(Bp + (size_t)k * N);
        float av[16];
        const float* ar = &aT[k][rbase];
        *(float4*)&av[0]  = *(const float4*)(ar);
        *(float4*)&av[4]  = *(const float4*)(ar + 4);
        *(float4*)&av[8]  = *(const float4*)(ar + 8);
        *(float4*)&av[12] = *(const float4*)(ar + 12);
        #pragma unroll
        for (int r = 0; r < 16; ++r) {
            acc[r][0] += av[r] * b4.x;
            acc[r][1] += av[r] * b4.y;
            acc[r][2] += av[r] * b4.z;
            acc[r][3] += av[r] * b4.w;
        }
    }
    #pragma unroll
    for (int r = 0; r < 16; ++r) {
        int row = row0 + rbase + r;
        if (row < M) {
            float4 o; o.x = acc[r][0]; o.y = acc[r][1]; o.z = acc[r][2]; o.w = acc[r][3];
            *(float4*)(C + (size_t)row * N + jq * 4) = o;
        }
    }
}

// ---------------- Layer 1 (H=8, C=16) ----------------
// One node per WAVE; wave = 2 edge-slots x 32 lanes; lane holds 4 channels (float4).
// Head = (lane&31)>>2 (4 lanes/head -> 2-step logit reduce).
__global__ __launch_bounds__(256)
void node_fused1(const int* __restrict__ rowptr, const int* __restrict__ esrc,
                 const float* __restrict__ xl, const float* __restrict__ xr,
                 const float* __restrict__ att, const float* __restrict__ b1,
                 float* __restrict__ hout) {
    int wave = threadIdx.x >> 6;
    int lane = threadIdx.x & 63;
    int n = blockIdx.x * 4 + wave;            // grid=12500 exact
    int slot = lane >> 5;                     // 0..1
    int l = lane & 31;                        // channels 4l..4l+3
    int beg = rowptr[n], end = rowptr[n + 1];
    float4 xr4 = *(const float4*)(xr + (size_t)n * 128 + 4 * l);
    float4 at4 = *(const float4*)(att + 4 * l);
    float den = 0.0f;
    float4 acc = {0, 0, 0, 0};

    auto body = [&](int k) {
        int s = esrc[k];
        float4 xv = *(const float4*)(xl + (size_t)s * 128 + 4 * l);
        float v = at4.x * lrelu(xv.x + xr4.x) + at4.y * lrelu(xv.y + xr4.y)
                + at4.z * lrelu(xv.z + xr4.z) + at4.w * lrelu(xv.w + xr4.w);
        v += __shfl_xor(v, 1);
        v += __shfl_xor(v, 2);
        float p = __expf(v);
        den += p;
        acc.x += p * xv.x; acc.y += p * xv.y; acc.z += p * xv.z; acc.w += p * xv.w;
    };
    int k = beg + slot;
    for (; k + 2 < end; k += 4) { body(k); body(k + 2); }
    if (k < end) body(k);

    // merge the 2 slots
    acc.x += __shfl_xor(acc.x, 32);
    acc.y += __shfl_xor(acc.y, 32);
    acc.z += __shfl_xor(acc.z, 32);
    acc.w += __shfl_xor(acc.w, 32);
    den   += __shfl_xor(den, 32);
    if (slot == 0) {
        float4 b4 = *(const float4*)(b1 + 4 * l);
        float inv = 1.0f / (den + SM_EPS);
        float4 o;
        o.x = fmaxf(acc.x * inv + b4.x, 0.0f);
        o.y = fmaxf(acc.y * inv + b4.y, 0.0f);
        o.z = fmaxf(acc.z * inv + b4.z, 0.0f);
        o.w = fmaxf(acc.w * inv + b4.w, 0.0f);
        *(float4*)(hout + (size_t)n * 128 + 4 * l) = o;
    }
}

// ---------------- Layer 2 (H=1, C=64) + classifier ----------------
// One node per WAVE; wave = 4 edge-slots x 16 lanes; lane holds 4 channels.
__global__ __launch_bounds__(256)
void node_fused2(const int* __restrict__ rowptr, const int* __restrict__ esrc,
                 const float* __restrict__ xl, const float* __restrict__ xr,
                 const float* __restrict__ att, const float* __restrict__ b2v,
                 const float* __restrict__ Wc1, const float* __restrict__ bc1,
                 const float* __restrict__ Wc2, const float* __restrict__ bc2,
                 float* __restrict__ out_emb, float* __restrict__ out_logits) {
    __shared__ float embS[4][64];
    int wave = threadIdx.x >> 6;
    int lane = threadIdx.x & 63;
    int n = blockIdx.x * 4 + wave;
    int slot = lane >> 4;                     // 0..3
    int l = lane & 15;                        // channels 4l..4l+3
    int beg = rowptr[n], end = rowptr[n + 1];
    float4 xr4 = *(const float4*)(xr + (size_t)n * 64 + 4 * l);
    float4 at4 = *(const float4*)(att + 4 * l);
    float den = 0.0f;
    float4 acc = {0, 0, 0, 0};

    auto body = [&](int k) {
        int s = esrc[k];
        float4 xv = *(const float4*)(xl + (size_t)s * 64 + 4 * l);
        float v = at4.x * lrelu(xv.x + xr4.x) + at4.y * lrelu(xv.y + xr4.y)
                + at4.z * lrelu(xv.z + xr4.z) + at4.w * lrelu(xv.w + xr4.w);
        v += __shfl_xor(v, 1);
        v += __shfl_xor(v, 2);
        v += __shfl_xor(v, 4);
        v += __shfl_xor(v, 8);
        float p = __expf(v);
        den += p;
        acc.x += p * xv.x; acc.y += p * xv.y; acc.z += p * xv.z; acc.w += p * xv.w;
    };
    int k = beg + slot;
    for (; k + 4 < end; k += 8) { body(k); body(k + 4); }
    if (k < end) body(k);

    // merge the 4 slots
    #pragma unroll
    for (int off = 16; off < 64; off <<= 1) {
        acc.x += __shfl_xor(acc.x, off);
        acc.y += __shfl_xor(acc.y, off);
        acc.z += __shfl_xor(acc.z, off);
        acc.w += __shfl_xor(acc.w, off);
        den   += __shfl_xor(den, off);
    }
    float inv = 1.0f / (den + SM_EPS);
    if (slot == 0) {
        float4 b4 = *(const float4*)(b2v + 4 * l);
        float4 e;
        e.x = acc.x * inv + b4.x;
        e.y = acc.y * inv + b4.y;
        e.z = acc.z * inv + b4.z;
        e.w = acc.w * inv + b4.w;
        *(float4*)(out_emb + (size_t)n * 64 + 4 * l) = e;
        *(float4*)&embS[wave][4 * l] = e;     // same-wave LDS, no barrier needed
    }

    // classifier: t = relu(emb@Wc1 + bc1)[128]; logits = t@Wc2 + bc2
    int j = lane;                              // 0..63
    float t0 = bc1[j], t1 = bc1[j + 64];
    #pragma unroll
    for (int kk = 0; kk < 64; kk += 4) {
        float4 e4 = *(const float4*)&embS[wave][kk];
        t0 += e4.x * Wc1[(kk + 0) * 128 + j] + e4.y * Wc1[(kk + 1) * 128 + j]
            + e4.z * Wc1[(kk + 2) * 128 + j] + e4.w * Wc1[(kk + 3) * 128 + j];
        t1 += e4.x * Wc1[(kk + 0) * 128 + 64 + j] + e4.y * Wc1[(kk + 1) * 128 + 64 + j]
            + e4.z * Wc1[(kk + 2) * 128 + 64 + j] + e4.w * Wc1[(kk + 3) * 128 + 64 + j];
    }
    t0 = fmaxf(t0, 0.0f);
    t1 = fmaxf(t1, 0.0f);
    float v0 = t0 * Wc2[2 * j]     + t1 * Wc2[2 * (j + 64)];
    float v1 = t0 * Wc2[2 * j + 1] + t1 * Wc2[2 * (j + 64) + 1];
    #pragma unroll
    for (int off = 1; off < 64; off <<= 1) {
        v0 += __shfl_xor(v0, off);
        v1 += __shfl_xor(v1, off);
    }
    if (lane == 0) {
        out_logits[(size_t)n * 2 + 0] = v0 + bc2[0];
        out_logits[(size_t)n * 2 + 1] = v1 + bc2[1];
    }
}

extern "C" void kernel_launch(void* const* d_in, const int* in_sizes, int n_in,
                              void* d_out, int out_size, void* d_ws, size_t ws_size,
                              hipStream_t stream) {
    const float* x    = (const float*)d_in[0];
    const int*   ei   = (const int*)d_in[1];
    const float* Wl1  = (const float*)d_in[3];
    const float* Wr1  = (const float*)d_in[4];
    const float* att1 = (const float*)d_in[5];
    const float* b1   = (const float*)d_in[6];
    const float* Wl2  = (const float*)d_in[7];
    const float* Wr2  = (const float*)d_in[8];
    const float* att2 = (const float*)d_in[9];
    const float* b2   = (const float*)d_in[10];
    const float* Wc1  = (const float*)d_in[15];
    const float* bc1  = (const float*)d_in[16];
    const float* Wc2  = (const float*)d_in[17];
    const float* bc2  = (const float*)d_in[18];

    float* ws = (float*)d_ws;
    int* flag   = (int*)ws;                        // 16
    int* deg    = flag + 16;                       // 50000   (deg+cnt zeroed by one memset)
    int* cnt    = deg + 50000;                     // 50000
    int* rowptr = cnt + 50000;                     // 50001 -> pad 50016
    int* esrc   = rowptr + 50016;                  // 850000
    int* bsum   = esrc + 850000;                   // 256
    float* xl1  = ws + 1000448;                    // 6.40M (layer2 xl2 in first 3.2M)
    float* xr1  = ws + 7400448;                    // 6.40M (layer2 xr2)
    float* hbuf = ws + 13800448;                   // 6.40M

    float* out_emb    = (float*)d_out;
    float* out_logits = out_emb + (size_t)N_NODES * 64;

    const int B = 256;
    #define GRID(n) (((n) + B - 1) / B)

    // ---- CSR build ----
    detect_layout<<<1, 256, 0, stream>>>(ei, flag);
    hipMemsetAsync(deg, 0, 2 * 50000 * sizeof(int), stream);
    count_deg<<<GRID(N_EDGES), B, 0, stream>>>(ei, flag, deg);
    scan_local<<<SCAN_B, 256, 0, stream>>>(deg, rowptr, bsum);
    scan_bsum<<<1, 256, 0, stream>>>(bsum);
    scan_add<<<SCAN_B, 256, 0, stream>>>(rowptr, bsum, esrc);
    scatter_edges<<<GRID(N_EDGES), B, 0, stream>>>(ei, flag, rowptr, cnt, esrc);

    // ---- layer 1 ----
    gemm_pair<128><<<1563, 128, 0, stream>>>(x, Wl1, Wr1, xl1, xr1, N_NODES);
    node_fused1<<<12500, 256, 0, stream>>>(rowptr, esrc, xl1, xr1, att1, b1, hbuf);

    // ---- layer 2 + classifier ----
    gemm_pair<64><<<1563, 64, 0, stream>>>(hbuf, Wl2, Wr2, xl1, xr1, N_NODES);
    node_fused2<<<12500, 256, 0, stream>>>(rowptr, esrc, xl1, xr1, att2, b2,
                                           Wc1, bc1, Wc2, bc2, out_emb, out_logits);
    #undef GRID
}

// Round 8
// 459.643 us; speedup vs baseline: 21.4555x; 1.0199x over previous
//
#include <hip/hip_runtime.h>
#include <hip/hip_bf16.h>
#include <cfloat>

#define N_NODES 50000
#define N_EDGES 800000
#define E_TOT   850000   /* edges + self-loops */
#define NEG_SLOPE 0.2f
#define SM_EPS 1e-16f
#define SCAN_B 196       /* ceil(50000/256) */

__device__ __forceinline__ float lrelu(float v) { return v > 0.0f ? v : NEG_SLOPE * v; }

// ---- CSR build -------------------------------------------------------------
// Layout detect (per block): int64 edge_index has all odd 32-bit words zero
// (ids < 50000); int32 layout has random src ids there. 256 probes -> exact.

__global__ void count_deg(const int* __restrict__ ei, int* __restrict__ deg) {
    int nz = __syncthreads_or(ei[2 * threadIdx.x + 1]);   // 0 => int64 layout
    int i = blockIdx.x * blockDim.x + threadIdx.x;        // edge-pair index
    if (2 * i >= N_EDGES) return;
    bool has2 = (2 * i + 1 < N_EDGES);
    if (nz) {  // int32: [src[E], dst[E]]
        int2 dp = *(const int2*)(ei + N_EDGES + 2 * i);
        atomicAdd(&deg[dp.x], 1);
        if (has2) atomicAdd(&deg[dp.y], 1);
    } else {   // int64: lo words at even indices
        int4 dp = *(const int4*)(ei + 2 * N_EDGES + 4 * i);
        atomicAdd(&deg[dp.x], 1);
        if (has2) atomicAdd(&deg[dp.z], 1);
    }
}

// blocked exclusive scan; +1 per node folds in the self-loop
__global__ void scan_local(const int* __restrict__ deg, int* __restrict__ rowptr,
                           int* __restrict__ bsum) {
    __shared__ int sh[256];
    int b = blockIdx.x, t = threadIdx.x, i = b * 256 + t;
    int v = (i < N_NODES) ? deg[i] + 1 : 0;
    sh[t] = v;
    __syncthreads();
    int val = v;
    for (int off = 1; off < 256; off <<= 1) {
        int add = (t >= off) ? sh[t - off] : 0;
        __syncthreads();
        val += add; sh[t] = val;
        __syncthreads();
    }
    if (i < N_NODES) rowptr[i] = val - v;
    if (t == 255) bsum[b] = val;
}

__global__ void scan_bsum(int* __restrict__ bsum) {
    __shared__ int sh[256];
    int t = threadIdx.x;
    int v = (t < SCAN_B) ? bsum[t] : 0;
    sh[t] = v;
    __syncthreads();
    int val = v;
    for (int off = 1; off < 256; off <<= 1) {
        int add = (t >= off) ? sh[t - off] : 0;
        __syncthreads();
        val += add; sh[t] = val;
        __syncthreads();
    }
    if (t < SCAN_B) bsum[t] = val - v;
}

__global__ void scan_add(int* __restrict__ rowptr, const int* __restrict__ bsum,
                         int* __restrict__ esrc) {
    int b = blockIdx.x, t = threadIdx.x, i = b * 256 + t;
    if (i < N_NODES) {
        int rp = rowptr[i] + bsum[b];
        rowptr[i] = rp;
        esrc[rp] = i;       // self-loop first
    }
    if (i == 0) rowptr[N_NODES] = E_TOT;
}

__global__ void scatter_edges(const int* __restrict__ ei, const int* __restrict__ rowptr,
                              int* __restrict__ cnt, int* __restrict__ esrc) {
    int nz = __syncthreads_or(ei[2 * threadIdx.x + 1]);
    int i = blockIdx.x * blockDim.x + threadIdx.x;
    if (2 * i >= N_EDGES) return;
    bool has2 = (2 * i + 1 < N_EDGES);
    int s0, d0, s1 = 0, d1 = 0;
    if (nz) {
        int2 sp = *(const int2*)(ei + 2 * i);
        int2 dp = *(const int2*)(ei + N_EDGES + 2 * i);
        s0 = sp.x; s1 = sp.y; d0 = dp.x; d1 = dp.y;
    } else {
        int4 sp = *(const int4*)(ei + 4 * i);
        int4 dp = *(const int4*)(ei + 2 * N_EDGES + 4 * i);
        s0 = sp.x; s1 = sp.z; d0 = dp.x; d1 = dp.z;
    }
    int p0 = rowptr[d0] + 1 + atomicAdd(&cnt[d0], 1);
    esrc[p0] = s0;
    if (has2) {
        int p1 = rowptr[d1] + 1 + atomicAdd(&cnt[d1], 1);
        esrc[p1] = s1;
    }
}

// ---------------- GEMM pair: C0 = A@B0, C1 = A@B1 ; A[M,128], B[128,N] ----------------
template<int N>
__global__ __launch_bounds__(4*(N/4))
void gemm_pair(const float* __restrict__ A, const float* __restrict__ B0,
               const float* __restrict__ B1, float* __restrict__ C0,
               float* __restrict__ C1, int M) {
    const int JQ = N / 4;
    const int NT = 4 * JQ;
    __shared__ float aT[128][36];
    int t = threadIdx.x;
    int jq    = t & (JQ - 1);
    int rh    = (t / JQ) & 1;
    int which = t / (2 * JQ);
    const float* B = which ? B1 : B0;
    float*       C = which ? C1 : C0;
    int row0 = blockIdx.x * 32;
    for (int i = t; i < 32 * 128; i += NT) {
        int r = i >> 7, kk = i & 127;
        int row = row0 + r;
        aT[kk][r] = (row < M) ? A[(size_t)row * 128 + kk] : 0.0f;
    }
    __syncthreads();
    float acc[16][4];
    #pragma unroll
    for (int r = 0; r < 16; ++r)
        #pragma unroll
        for (int c = 0; c < 4; ++c) acc[r][c] = 0.0f;
    const float* Bp = B + jq * 4;
    const int rbase = rh * 16;
    for (int k = 0; k < 128; ++k) {
        float4 b4 = *(const float4*)(Bp + (size_t)k * N);
        float av[16];
        const float* ar = &aT[k][rbase];
        *(float4*)&av[0]  = *(const float4*)(ar);
        *(float4*)&av[4]  = *(const float4*)(ar + 4);
        *(float4*)&av[8]  = *(const float4*)(ar + 8);
        *(float4*)&av[12] = *(const float4*)(ar + 12);
        #pragma unroll
        for (int r = 0; r < 16; ++r) {
            acc[r][0] += av[r] * b4.x;
            acc[r][1] += av[r] * b4.y;
            acc[r][2] += av[r] * b4.z;
            acc[r][3] += av[r] * b4.w;
        }
    }
    #pragma unroll
    for (int r = 0; r < 16; ++r) {
        int row = row0 + rbase + r;
        if (row < M) {
            float4 o; o.x = acc[r][0]; o.y = acc[r][1]; o.z = acc[r][2]; o.w = acc[r][3];
            *(float4*)(C + (size_t)row * N + jq * 4) = o;
        }
    }
}

// ---------------- Layer 1 (H=8, C=16) ----------------
// Node per wave; wave = 4 edge-slots x 16 lanes; lane holds 8 channels (2xfloat4).
// Head = 2 lanes -> 1-step logit reduce.
__global__ __launch_bounds__(256)
void node_fused1(const int* __restrict__ rowptr, const int* __restrict__ esrc,
                 const float* __restrict__ xl, const float* __restrict__ xr,
                 const float* __restrict__ att, const float* __restrict__ b1,
                 float* __restrict__ hout) {
    int wave = threadIdx.x >> 6;
    int lane = threadIdx.x & 63;
    int n = blockIdx.x * 4 + wave;            // grid = 12500 exact
    int slot = lane >> 4;                     // 0..3
    int l = lane & 15;                        // channels 8l..8l+7
    int beg = rowptr[n], end = rowptr[n + 1];
    const float* xrp = xr + (size_t)n * 128 + 8 * l;
    float4 xra = *(const float4*)(xrp);
    float4 xrb = *(const float4*)(xrp + 4);
    float4 ata = *(const float4*)(att + 8 * l);
    float4 atb = *(const float4*)(att + 8 * l + 4);
    float den = 0.0f;
    float4 aa = {0, 0, 0, 0}, ab = {0, 0, 0, 0};

    auto body = [&](int k) {
        int s = esrc[k];
        const float* xp = xl + (size_t)s * 128 + 8 * l;
        float4 xa = *(const float4*)(xp);
        float4 xb = *(const float4*)(xp + 4);
        float v = ata.x * lrelu(xa.x + xra.x) + ata.y * lrelu(xa.y + xra.y)
                + ata.z * lrelu(xa.z + xra.z) + ata.w * lrelu(xa.w + xra.w)
                + atb.x * lrelu(xb.x + xrb.x) + atb.y * lrelu(xb.y + xrb.y)
                + atb.z * lrelu(xb.z + xrb.z) + atb.w * lrelu(xb.w + xrb.w);
        v += __shfl_xor(v, 1);                // combine the head's two lanes
        float p = __expf(v);
        den += p;
        aa.x += p * xa.x; aa.y += p * xa.y; aa.z += p * xa.z; aa.w += p * xa.w;
        ab.x += p * xb.x; ab.y += p * xb.y; ab.z += p * xb.z; ab.w += p * xb.w;
    };
    int k = beg + slot;
    for (; k + 4 < end; k += 8) { body(k); body(k + 4); }
    if (k < end) body(k);

    // merge 4 slots
    #pragma unroll
    for (int off = 16; off < 64; off <<= 1) {
        aa.x += __shfl_xor(aa.x, off); aa.y += __shfl_xor(aa.y, off);
        aa.z += __shfl_xor(aa.z, off); aa.w += __shfl_xor(aa.w, off);
        ab.x += __shfl_xor(ab.x, off); ab.y += __shfl_xor(ab.y, off);
        ab.z += __shfl_xor(ab.z, off); ab.w += __shfl_xor(ab.w, off);
        den   += __shfl_xor(den, off);
    }
    if (slot == 0) {
        float inv = 1.0f / (den + SM_EPS);
        float4 b4a = *(const float4*)(b1 + 8 * l);
        float4 b4b = *(const float4*)(b1 + 8 * l + 4);
        float4 oa, ob;
        oa.x = fmaxf(aa.x * inv + b4a.x, 0.0f);
        oa.y = fmaxf(aa.y * inv + b4a.y, 0.0f);
        oa.z = fmaxf(aa.z * inv + b4a.z, 0.0f);
        oa.w = fmaxf(aa.w * inv + b4a.w, 0.0f);
        ob.x = fmaxf(ab.x * inv + b4b.x, 0.0f);
        ob.y = fmaxf(ab.y * inv + b4b.y, 0.0f);
        ob.z = fmaxf(ab.z * inv + b4b.z, 0.0f);
        ob.w = fmaxf(ab.w * inv + b4b.w, 0.0f);
        float* op = hout + (size_t)n * 128 + 8 * l;
        *(float4*)(op)     = oa;
        *(float4*)(op + 4) = ob;
    }
}

// ---------------- Layer 2 (H=1, C=64) ----------------
// Node per wave; wave = 8 edge-slots x 8 lanes; lane holds 8 channels.
__global__ __launch_bounds__(256)
void node_fused2(const int* __restrict__ rowptr, const int* __restrict__ esrc,
                 const float* __restrict__ xl, const float* __restrict__ xr,
                 const float* __restrict__ att, const float* __restrict__ b2v,
                 float* __restrict__ out_emb) {
    int wave = threadIdx.x >> 6;
    int lane = threadIdx.x & 63;
    int n = blockIdx.x * 4 + wave;
    int slot = lane >> 3;                     // 0..7
    int l = lane & 7;                         // channels 8l..8l+7
    int beg = rowptr[n], end = rowptr[n + 1];
    const float* xrp = xr + (size_t)n * 64 + 8 * l;
    float4 xra = *(const float4*)(xrp);
    float4 xrb = *(const float4*)(xrp + 4);
    float4 ata = *(const float4*)(att + 8 * l);
    float4 atb = *(const float4*)(att + 8 * l + 4);
    float den = 0.0f;
    float4 aa = {0, 0, 0, 0}, ab = {0, 0, 0, 0};

    auto body = [&](int k) {
        int s = esrc[k];
        const float* xp = xl + (size_t)s * 64 + 8 * l;
        float4 xa = *(const float4*)(xp);
        float4 xb = *(const float4*)(xp + 4);
        float v = ata.x * lrelu(xa.x + xra.x) + ata.y * lrelu(xa.y + xra.y)
                + ata.z * lrelu(xa.z + xra.z) + ata.w * lrelu(xa.w + xra.w)
                + atb.x * lrelu(xb.x + xrb.x) + atb.y * lrelu(xb.y + xrb.y)
                + atb.z * lrelu(xb.z + xrb.z) + atb.w * lrelu(xb.w + xrb.w);
        v += __shfl_xor(v, 1);
        v += __shfl_xor(v, 2);
        v += __shfl_xor(v, 4);
        float p = __expf(v);
        den += p;
        aa.x += p * xa.x; aa.y += p * xa.y; aa.z += p * xa.z; aa.w += p * xa.w;
        ab.x += p * xb.x; ab.y += p * xb.y; ab.z += p * xb.z; ab.w += p * xb.w;
    };
    int k = beg + slot;
    for (; k + 8 < end; k += 16) { body(k); body(k + 8); }
    if (k < end) body(k);

    // merge 8 slots
    #pragma unroll
    for (int off = 8; off < 64; off <<= 1) {
        aa.x += __shfl_xor(aa.x, off); aa.y += __shfl_xor(aa.y, off);
        aa.z += __shfl_xor(aa.z, off); aa.w += __shfl_xor(aa.w, off);
        ab.x += __shfl_xor(ab.x, off); ab.y += __shfl_xor(ab.y, off);
        ab.z += __shfl_xor(ab.z, off); ab.w += __shfl_xor(ab.w, off);
        den   += __shfl_xor(den, off);
    }
    if (slot == 0) {
        float inv = 1.0f / (den + SM_EPS);
        float4 b4a = *(const float4*)(b2v + 8 * l);
        float4 b4b = *(const float4*)(b2v + 8 * l + 4);
        float4 ea, eb;
        ea.x = aa.x * inv + b4a.x; ea.y = aa.y * inv + b4a.y;
        ea.z = aa.z * inv + b4a.z; ea.w = aa.w * inv + b4a.w;
        eb.x = ab.x * inv + b4b.x; eb.y = ab.y * inv + b4b.y;
        eb.z = ab.z * inv + b4b.z; eb.w = ab.w * inv + b4b.w;
        float* op = out_emb + (size_t)n * 64 + 8 * l;
        *(float4*)(op)     = ea;
        *(float4*)(op + 4) = eb;
    }
}

// ---------------- Classifier: LDS-tiled ----------------
// 32 nodes/block, 256 threads. t = relu(emb@Wc1 + bc1)[128]; logits = t@Wc2 + bc2.
#define CLS_NODES 32
__global__ __launch_bounds__(256)
void classifier(const float* __restrict__ emb, const float* __restrict__ Wc1,
                const float* __restrict__ bc1, const float* __restrict__ Wc2,
                const float* __restrict__ bc2, float* __restrict__ out_logits) {
    __shared__ float w1[64 * 128];            // 32 KB, row-major [64][128]
    __shared__ float eS[CLS_NODES][64];       // 8 KB
    __shared__ float tS[CLS_NODES][132];      // 16.9 KB (pad 132 breaks phase-C conflicts)
    int t = threadIdx.x;
    int n0 = blockIdx.x * CLS_NODES;
    for (int i = t; i < 64 * 128 / 4; i += 256)
        ((float4*)w1)[i] = ((const float4*)Wc1)[i];
    for (int i = t; i < CLS_NODES * 64 / 4; i += 256) {
        size_t off = (size_t)n0 * 64 + i * 4;
        float4 v = {0, 0, 0, 0};
        if (off + 3 < (size_t)N_NODES * 64) v = *(const float4*)(emb + off);
        ((float4*)eS)[i] = v;
    }
    __syncthreads();
    // phase B: 2 planes of 128 cols
    int jj = t & 127, half = t >> 7;
    for (int nn = half; nn < CLS_NODES; nn += 2) {
        float a0 = 0, a1 = 0, a2 = 0, a3 = 0;
        #pragma unroll
        for (int k = 0; k < 64; k += 4) {
            a0 += eS[nn][k]     * w1[(k)     * 128 + jj];
            a1 += eS[nn][k + 1] * w1[(k + 1) * 128 + jj];
            a2 += eS[nn][k + 2] * w1[(k + 2) * 128 + jj];
            a3 += eS[nn][k + 3] * w1[(k + 3) * 128 + jj];
        }
        tS[nn][jj] = fmaxf(bc1[jj] + (a0 + a1) + (a2 + a3), 0.0f);
    }
    __syncthreads();
    // phase C: node = t>>3 (32 nodes), seg = t&7 (16 cols each)
    int node = t >> 3, seg = t & 7;
    float v0 = 0, v1 = 0;
    #pragma unroll
    for (int c = 0; c < 16; ++c) {
        float tv = tS[node][seg * 16 + c];
        v0 += tv * Wc2[2 * (seg * 16 + c)];
        v1 += tv * Wc2[2 * (seg * 16 + c) + 1];
    }
    v0 += __shfl_xor(v0, 1); v1 += __shfl_xor(v1, 1);
    v0 += __shfl_xor(v0, 2); v1 += __shfl_xor(v1, 2);
    v0 += __shfl_xor(v0, 4); v1 += __shfl_xor(v1, 4);
    int n = n0 + node;
    if (seg == 0 && n < N_NODES) {
        out_logits[(size_t)n * 2 + 0] = v0 + bc2[0];
        out_logits[(size_t)n * 2 + 1] = v1 + bc2[1];
    }
}

extern "C" void kernel_launch(void* const* d_in, const int* in_sizes, int n_in,
                              void* d_out, int out_size, void* d_ws, size_t ws_size,
                              hipStream_t stream) {
    const float* x    = (const float*)d_in[0];
    const int*   ei   = (const int*)d_in[1];
    const float* Wl1  = (const float*)d_in[3];
    const float* Wr1  = (const float*)d_in[4];
    const float* att1 = (const float*)d_in[5];
    const float* b1   = (const float*)d_in[6];
    const float* Wl2  = (const float*)d_in[7];
    const float* Wr2  = (const float*)d_in[8];
    const float* att2 = (const float*)d_in[9];
    const float* b2   = (const float*)d_in[10];
    const float* Wc1  = (const float*)d_in[15];
    const float* bc1  = (const float*)d_in[16];
    const float* Wc2  = (const float*)d_in[17];
    const float* bc2  = (const float*)d_in[18];

    float* ws = (float*)d_ws;
    int* deg    = (int*)ws;                        // 50000  (deg+cnt zeroed by one memset)
    int* cnt    = deg + 50000;                     // 50000
    int* rowptr = cnt + 50000;                     // 50001 -> pad 50016
    int* esrc   = rowptr + 50016;                  // 850000
    int* bsum   = esrc + 850000;                   // 256
    float* xl1  = ws + 1000448;                    // 6.40M (layer2 xl2 in first 3.2M)
    float* xr1  = ws + 7400448;                    // 6.40M (layer2 xr2)
    float* hbuf = ws + 13800448;                   // 6.40M

    float* out_emb    = (float*)d_out;
    float* out_logits = out_emb + (size_t)N_NODES * 64;

    // ---- CSR build ----
    hipMemsetAsync(deg, 0, 2 * 50000 * sizeof(int), stream);
    count_deg<<<1563, 256, 0, stream>>>(ei, deg);              // 2 edges/thread
    scan_local<<<SCAN_B, 256, 0, stream>>>(deg, rowptr, bsum);
    scan_bsum<<<1, 256, 0, stream>>>(bsum);
    scan_add<<<SCAN_B, 256, 0, stream>>>(rowptr, bsum, esrc);
    scatter_edges<<<1563, 256, 0, stream>>>(ei, rowptr, cnt, esrc);

    // ---- layer 1 ----
    gemm_pair<128><<<1563, 128, 0, stream>>>(x, Wl1, Wr1, xl1, xr1, N_NODES);
    node_fused1<<<12500, 256, 0, stream>>>(rowptr, esrc, xl1, xr1, att1, b1, hbuf);

    // ---- layer 2 ----
    gemm_pair<64><<<1563, 64, 0, stream>>>(hbuf, Wl2, Wr2, xl1, xr1, N_NODES);
    node_fused2<<<12500, 256, 0, stream>>>(rowptr, esrc, xl1, xr1, att2, b2, out_emb);

    // ---- classifier ----
    classifier<<<1563, 256, 0, stream>>>(out_emb, Wc1, bc1, Wc2, bc2, out_logits);
}

// Round 9
// 430.536 us; speedup vs baseline: 22.9060x; 1.0676x over previous
//
#include <hip/hip_runtime.h>
#include <hip/hip_bf16.h>
#include <cfloat>

#define N_NODES 50000
#define N_EDGES 800000
#define E_TOT   850000   /* edges + self-loops */
#define NEG_SLOPE 0.2f
#define SM_EPS 1e-16f
#define SCAN_B 196       /* ceil(50000/256) */

__device__ __forceinline__ float lrelu(float v) { return v > 0.0f ? v : NEG_SLOPE * v; }

// ---- CSR build -------------------------------------------------------------
// Layout detect (per block): int64 edge_index has all odd 32-bit words zero
// (ids < 50000); int32 layout has random src ids there. 256 probes -> exact.

__global__ void count_deg(const int* __restrict__ ei, int* __restrict__ deg) {
    int nz = __syncthreads_or(ei[2 * threadIdx.x + 1]);   // 0 => int64 layout
    int i = blockIdx.x * blockDim.x + threadIdx.x;        // edge-pair index
    if (2 * i >= N_EDGES) return;
    bool has2 = (2 * i + 1 < N_EDGES);
    if (nz) {  // int32: [src[E], dst[E]]
        int2 dp = *(const int2*)(ei + N_EDGES + 2 * i);
        atomicAdd(&deg[dp.x], 1);
        if (has2) atomicAdd(&deg[dp.y], 1);
    } else {   // int64: lo words at even indices
        int4 dp = *(const int4*)(ei + 2 * N_EDGES + 4 * i);
        atomicAdd(&deg[dp.x], 1);
        if (has2) atomicAdd(&deg[dp.z], 1);
    }
}

// blocked exclusive scan; +1 per node folds in the self-loop
__global__ void scan_local(const int* __restrict__ deg, int* __restrict__ rowptr,
                           int* __restrict__ bsum) {
    __shared__ int sh[256];
    int b = blockIdx.x, t = threadIdx.x, i = b * 256 + t;
    int v = (i < N_NODES) ? deg[i] + 1 : 0;
    sh[t] = v;
    __syncthreads();
    int val = v;
    for (int off = 1; off < 256; off <<= 1) {
        int add = (t >= off) ? sh[t - off] : 0;
        __syncthreads();
        val += add; sh[t] = val;
        __syncthreads();
    }
    if (i < N_NODES) rowptr[i] = val - v;
    if (t == 255) bsum[b] = val;
}

// add block offsets (local tree-sum over preceding block sums);
// write self-loop into slot 0 of each node's segment
__global__ void scan_add(int* __restrict__ rowptr, const int* __restrict__ bsum,
                         int* __restrict__ esrc) {
    __shared__ int sh[256];
    int b = blockIdx.x, t = threadIdx.x;
    sh[t] = (t < b && t < SCAN_B) ? bsum[t] : 0;
    __syncthreads();
    #pragma unroll
    for (int off = 128; off; off >>= 1) {
        if (t < off) sh[t] += sh[t + off];
        __syncthreads();
    }
    int offset = sh[0];
    int i = b * 256 + t;
    if (i < N_NODES) {
        int rp = rowptr[i] + offset;
        rowptr[i] = rp;
        esrc[rp] = i;       // self-loop first
    }
    if (i == 0) rowptr[N_NODES] = E_TOT;
}

__global__ void scatter_edges(const int* __restrict__ ei, const int* __restrict__ rowptr,
                              int* __restrict__ cnt, int* __restrict__ esrc) {
    int nz = __syncthreads_or(ei[2 * threadIdx.x + 1]);
    int i = blockIdx.x * blockDim.x + threadIdx.x;
    if (2 * i >= N_EDGES) return;
    bool has2 = (2 * i + 1 < N_EDGES);
    int s0, d0, s1 = 0, d1 = 0;
    if (nz) {
        int2 sp = *(const int2*)(ei + 2 * i);
        int2 dp = *(const int2*)(ei + N_EDGES + 2 * i);
        s0 = sp.x; s1 = sp.y; d0 = dp.x; d1 = dp.y;
    } else {
        int4 sp = *(const int4*)(ei + 4 * i);
        int4 dp = *(const int4*)(ei + 2 * N_EDGES + 4 * i);
        s0 = sp.x; s1 = sp.z; d0 = dp.x; d1 = dp.z;
    }
    int p0 = rowptr[d0] + 1 + atomicAdd(&cnt[d0], 1);
    esrc[p0] = s0;
    if (has2) {
        int p1 = rowptr[d1] + 1 + atomicAdd(&cnt[d1], 1);
        esrc[p1] = s1;
    }
}

// ---------------- GEMM pair: C0 = A@B0, C1 = A@B1 ; A[M,128], B[128,N] ----------------
// 256 threads, 32 rows/block, register-double-buffered k-loop.
// Thread tile: RPT rows x 4 cols (RPT = 8 for N=128, 4 for N=64).
template<int N>
__global__ __launch_bounds__(256)
void gemm_pair(const float* __restrict__ A, const float* __restrict__ B0,
               const float* __restrict__ B1, float* __restrict__ C0,
               float* __restrict__ C1, int M) {
    constexpr int JQ  = N / 4;          // col quads
    constexpr int RG  = 128 / JQ;       // row groups (threads = JQ*RG*2 = 256)
    constexpr int RPT = 32 / RG;        // rows per thread
    __shared__ float aT[128][36];
    int t = threadIdx.x;
    int jq    = t % JQ;
    int rg    = (t / JQ) % RG;
    int which = t / 128;
    const float* B = which ? B1 : B0;
    float*       C = which ? C1 : C0;
    int row0 = blockIdx.x * 32;
    for (int i = t; i < 32 * 128; i += 256) {
        int r = i >> 7, kk = i & 127;
        int row = row0 + r;
        aT[kk][r] = (row < M) ? A[(size_t)row * 128 + kk] : 0.0f;
    }
    __syncthreads();
    float acc[RPT][4];
    #pragma unroll
    for (int r = 0; r < RPT; ++r)
        #pragma unroll
        for (int c = 0; c < 4; ++c) acc[r][c] = 0.0f;
    const float* Bp = B + jq * 4;
    const int rbase = rg * RPT;
    float4 b4 = *(const float4*)(Bp);
    float av[RPT];
    #pragma unroll
    for (int q = 0; q < RPT; q += 4)
        *(float4*)&av[q] = *(const float4*)&aT[0][rbase + q];
    for (int k = 0; k < 127; ++k) {
        float4 b4n = *(const float4*)(Bp + (size_t)(k + 1) * N);
        float avn[RPT];
        #pragma unroll
        for (int q = 0; q < RPT; q += 4)
            *(float4*)&avn[q] = *(const float4*)&aT[k + 1][rbase + q];
        #pragma unroll
        for (int r = 0; r < RPT; ++r) {
            acc[r][0] += av[r] * b4.x;
            acc[r][1] += av[r] * b4.y;
            acc[r][2] += av[r] * b4.z;
            acc[r][3] += av[r] * b4.w;
        }
        b4 = b4n;
        #pragma unroll
        for (int r = 0; r < RPT; ++r) av[r] = avn[r];
    }
    #pragma unroll
    for (int r = 0; r < RPT; ++r) {
        acc[r][0] += av[r] * b4.x;
        acc[r][1] += av[r] * b4.y;
        acc[r][2] += av[r] * b4.z;
        acc[r][3] += av[r] * b4.w;
    }
    #pragma unroll
    for (int r = 0; r < RPT; ++r) {
        int row = row0 + rbase + r;
        if (row < M) {
            float4 o; o.x = acc[r][0]; o.y = acc[r][1]; o.z = acc[r][2]; o.w = acc[r][3];
            *(float4*)(C + (size_t)row * N + jq * 4) = o;
        }
    }
}

// ---------------- Layer 1 (H=8, C=16) ----------------
// Node per wave; wave = 4 edge-slots x 16 lanes; lane holds 8 channels (2xfloat4).
__global__ __launch_bounds__(256)
void node_fused1(const int* __restrict__ rowptr, const int* __restrict__ esrc,
                 const float* __restrict__ xl, const float* __restrict__ xr,
                 const float* __restrict__ att, const float* __restrict__ b1,
                 float* __restrict__ hout) {
    int wave = threadIdx.x >> 6;
    int lane = threadIdx.x & 63;
    int n = blockIdx.x * 4 + wave;            // grid = 12500 exact
    int slot = lane >> 4;                     // 0..3
    int l = lane & 15;                        // channels 8l..8l+7
    int beg = rowptr[n], end = rowptr[n + 1];
    const float* xrp = xr + (size_t)n * 128 + 8 * l;
    float4 xra = *(const float4*)(xrp);
    float4 xrb = *(const float4*)(xrp + 4);
    float4 ata = *(const float4*)(att + 8 * l);
    float4 atb = *(const float4*)(att + 8 * l + 4);
    float den = 0.0f;
    float4 aa = {0, 0, 0, 0}, ab = {0, 0, 0, 0};

    auto body = [&](int k) {
        int s = esrc[k];
        const float* xp = xl + (size_t)s * 128 + 8 * l;
        float4 xa = *(const float4*)(xp);
        float4 xb = *(const float4*)(xp + 4);
        float v = ata.x * lrelu(xa.x + xra.x) + ata.y * lrelu(xa.y + xra.y)
                + ata.z * lrelu(xa.z + xra.z) + ata.w * lrelu(xa.w + xra.w)
                + atb.x * lrelu(xb.x + xrb.x) + atb.y * lrelu(xb.y + xrb.y)
                + atb.z * lrelu(xb.z + xrb.z) + atb.w * lrelu(xb.w + xrb.w);
        v += __shfl_xor(v, 1);                // combine the head's two lanes
        float p = __expf(v);
        den += p;
        aa.x += p * xa.x; aa.y += p * xa.y; aa.z += p * xa.z; aa.w += p * xa.w;
        ab.x += p * xb.x; ab.y += p * xb.y; ab.z += p * xb.z; ab.w += p * xb.w;
    };
    int k = beg + slot;
    for (; k + 4 < end; k += 8) { body(k); body(k + 4); }
    if (k < end) body(k);

    // merge 4 slots
    #pragma unroll
    for (int off = 16; off < 64; off <<= 1) {
        aa.x += __shfl_xor(aa.x, off); aa.y += __shfl_xor(aa.y, off);
        aa.z += __shfl_xor(aa.z, off); aa.w += __shfl_xor(aa.w, off);
        ab.x += __shfl_xor(ab.x, off); ab.y += __shfl_xor(ab.y, off);
        ab.z += __shfl_xor(ab.z, off); ab.w += __shfl_xor(ab.w, off);
        den   += __shfl_xor(den, off);
    }
    if (slot == 0) {
        float inv = 1.0f / (den + SM_EPS);
        float4 b4a = *(const float4*)(b1 + 8 * l);
        float4 b4b = *(const float4*)(b1 + 8 * l + 4);
        float4 oa, ob;
        oa.x = fmaxf(aa.x * inv + b4a.x, 0.0f);
        oa.y = fmaxf(aa.y * inv + b4a.y, 0.0f);
        oa.z = fmaxf(aa.z * inv + b4a.z, 0.0f);
        oa.w = fmaxf(aa.w * inv + b4a.w, 0.0f);
        ob.x = fmaxf(ab.x * inv + b4b.x, 0.0f);
        ob.y = fmaxf(ab.y * inv + b4b.y, 0.0f);
        ob.z = fmaxf(ab.z * inv + b4b.z, 0.0f);
        ob.w = fmaxf(ab.w * inv + b4b.w, 0.0f);
        float* op = hout + (size_t)n * 128 + 8 * l;
        *(float4*)(op)     = oa;
        *(float4*)(op + 4) = ob;
    }
}

// ---------------- Layer 2 (H=1, C=64) ----------------
// Node per wave; wave = 8 edge-slots x 8 lanes; lane holds 8 channels.
__global__ __launch_bounds__(256)
void node_fused2(const int* __restrict__ rowptr, const int* __restrict__ esrc,
                 const float* __restrict__ xl, const float* __restrict__ xr,
                 const float* __restrict__ att, const float* __restrict__ b2v,
                 float* __restrict__ out_emb) {
    int wave = threadIdx.x >> 6;
    int lane = threadIdx.x & 63;
    int n = blockIdx.x * 4 + wave;
    int slot = lane >> 3;                     // 0..7
    int l = lane & 7;                         // channels 8l..8l+7
    int beg = rowptr[n], end = rowptr[n + 1];
    const float* xrp = xr + (size_t)n * 64 + 8 * l;
    float4 xra = *(const float4*)(xrp);
    float4 xrb = *(const float4*)(xrp + 4);
    float4 ata = *(const float4*)(att + 8 * l);
    float4 atb = *(const float4*)(att + 8 * l + 4);
    float den = 0.0f;
    float4 aa = {0, 0, 0, 0}, ab = {0, 0, 0, 0};

    auto body = [&](int k) {
        int s = esrc[k];
        const float* xp = xl + (size_t)s * 64 + 8 * l;
        float4 xa = *(const float4*)(xp);
        float4 xb = *(const float4*)(xp + 4);
        float v = ata.x * lrelu(xa.x + xra.x) + ata.y * lrelu(xa.y + xra.y)
                + ata.z * lrelu(xa.z + xra.z) + ata.w * lrelu(xa.w + xra.w)
                + atb.x * lrelu(xb.x + xrb.x) + atb.y * lrelu(xb.y + xrb.y)
                + atb.z * lrelu(xb.z + xrb.z) + atb.w * lrelu(xb.w + xrb.w);
        v += __shfl_xor(v, 1);
        v += __shfl_xor(v, 2);
        v += __shfl_xor(v, 4);
        float p = __expf(v);
        den += p;
        aa.x += p * xa.x; aa.y += p * xa.y; aa.z += p * xa.z; aa.w += p * xa.w;
        ab.x += p * xb.x; ab.y += p * xb.y; ab.z += p * xb.z; ab.w += p * xb.w;
    };
    int k = beg + slot;
    for (; k + 8 < end; k += 16) { body(k); body(k + 8); }
    if (k < end) body(k);

    // merge 8 slots
    #pragma unroll
    for (int off = 8; off < 64; off <<= 1) {
        aa.x += __shfl_xor(aa.x, off); aa.y += __shfl_xor(aa.y, off);
        aa.z += __shfl_xor(aa.z, off); aa.w += __shfl_xor(aa.w, off);
        ab.x += __shfl_xor(ab.x, off); ab.y += __shfl_xor(ab.y, off);
        ab.z += __shfl_xor(ab.z, off); ab.w += __shfl_xor(ab.w, off);
        den   += __shfl_xor(den, off);
    }
    if (slot == 0) {
        float inv = 1.0f / (den + SM_EPS);
        float4 b4a = *(const float4*)(b2v + 8 * l);
        float4 b4b = *(const float4*)(b2v + 8 * l + 4);
        float4 ea, eb;
        ea.x = aa.x * inv + b4a.x; ea.y = aa.y * inv + b4a.y;
        ea.z = aa.z * inv + b4a.z; ea.w = aa.w * inv + b4a.w;
        eb.x = ab.x * inv + b4b.x; eb.y = ab.y * inv + b4b.y;
        eb.z = ab.z * inv + b4b.z; eb.w = ab.w * inv + b4b.w;
        float* op = out_emb + (size_t)n * 64 + 8 * l;
        *(float4*)(op)     = ea;
        *(float4*)(op + 4) = eb;
    }
}

// ---------------- Classifier: LDS-tiled ----------------
#define CLS_NODES 32
__global__ __launch_bounds__(256)
void classifier(const float* __restrict__ emb, const float* __restrict__ Wc1,
                const float* __restrict__ bc1, const float* __restrict__ Wc2,
                const float* __restrict__ bc2, float* __restrict__ out_logits) {
    __shared__ float w1[64 * 128];            // 32 KB
    __shared__ float eS[CLS_NODES][64];       // 8 KB
    __shared__ float tS[CLS_NODES][132];      // pad 132 breaks phase-C conflicts
    int t = threadIdx.x;
    int n0 = blockIdx.x * CLS_NODES;
    for (int i = t; i < 64 * 128 / 4; i += 256)
        ((float4*)w1)[i] = ((const float4*)Wc1)[i];
    for (int i = t; i < CLS_NODES * 64 / 4; i += 256) {
        size_t off = (size_t)n0 * 64 + i * 4;
        float4 v = {0, 0, 0, 0};
        if (off + 3 < (size_t)N_NODES * 64) v = *(const float4*)(emb + off);
        ((float4*)eS)[i] = v;
    }
    __syncthreads();
    int jj = t & 127, half = t >> 7;
    for (int nn = half; nn < CLS_NODES; nn += 2) {
        float a0 = 0, a1 = 0, a2 = 0, a3 = 0;
        #pragma unroll
        for (int k = 0; k < 64; k += 4) {
            a0 += eS[nn][k]     * w1[(k)     * 128 + jj];
            a1 += eS[nn][k + 1] * w1[(k + 1) * 128 + jj];
            a2 += eS[nn][k + 2] * w1[(k + 2) * 128 + jj];
            a3 += eS[nn][k + 3] * w1[(k + 3) * 128 + jj];
        }
        tS[nn][jj] = fmaxf(bc1[jj] + (a0 + a1) + (a2 + a3), 0.0f);
    }
    __syncthreads();
    int node = t >> 3, seg = t & 7;
    float v0 = 0, v1 = 0;
    #pragma unroll
    for (int c = 0; c < 16; ++c) {
        float tv = tS[node][seg * 16 + c];
        v0 += tv * Wc2[2 * (seg * 16 + c)];
        v1 += tv * Wc2[2 * (seg * 16 + c) + 1];
    }
    v0 += __shfl_xor(v0, 1); v1 += __shfl_xor(v1, 1);
    v0 += __shfl_xor(v0, 2); v1 += __shfl_xor(v1, 2);
    v0 += __shfl_xor(v0, 4); v1 += __shfl_xor(v1, 4);
    int n = n0 + node;
    if (seg == 0 && n < N_NODES) {
        out_logits[(size_t)n * 2 + 0] = v0 + bc2[0];
        out_logits[(size_t)n * 2 + 1] = v1 + bc2[1];
    }
}

extern "C" void kernel_launch(void* const* d_in, const int* in_sizes, int n_in,
                              void* d_out, int out_size, void* d_ws, size_t ws_size,
                              hipStream_t stream) {
    const float* x    = (const float*)d_in[0];
    const int*   ei   = (const int*)d_in[1];
    const float* Wl1  = (const float*)d_in[3];
    const float* Wr1  = (const float*)d_in[4];
    const float* att1 = (const float*)d_in[5];
    const float* b1   = (const float*)d_in[6];
    const float* Wl2  = (const float*)d_in[7];
    const float* Wr2  = (const float*)d_in[8];
    const float* att2 = (const float*)d_in[9];
    const float* b2   = (const float*)d_in[10];
    const float* Wc1  = (const float*)d_in[15];
    const float* bc1  = (const float*)d_in[16];
    const float* Wc2  = (const float*)d_in[17];
    const float* bc2  = (const float*)d_in[18];

    float* ws = (float*)d_ws;
    int* deg    = (int*)ws;                        // 50000  (deg+cnt zeroed by one memset)
    int* cnt    = deg + 50000;                     // 50000
    int* rowptr = cnt + 50000;                     // 50001 -> pad 50016
    int* esrc   = rowptr + 50016;                  // 850000
    int* bsum   = esrc + 850000;                   // 256
    float* xl1  = ws + 1000448;                    // 6.40M (layer2 xl2 in first 3.2M)
    float* xr1  = ws + 7400448;                    // 6.40M (layer2 xr2)
    float* hbuf = ws + 13800448;                   // 6.40M

    float* out_emb    = (float*)d_out;
    float* out_logits = out_emb + (size_t)N_NODES * 64;

    // ---- CSR build ----
    hipMemsetAsync(deg, 0, 2 * 50000 * sizeof(int), stream);
    count_deg<<<1563, 256, 0, stream>>>(ei, deg);
    scan_local<<<SCAN_B, 256, 0, stream>>>(deg, rowptr, bsum);
    scan_add<<<SCAN_B, 256, 0, stream>>>(rowptr, bsum, esrc);
    scatter_edges<<<1563, 256, 0, stream>>>(ei, rowptr, cnt, esrc);

    // ---- layer 1 ----
    gemm_pair<128><<<1563, 256, 0, stream>>>(x, Wl1, Wr1, xl1, xr1, N_NODES);
    node_fused1<<<12500, 256, 0, stream>>>(rowptr, esrc, xl1, xr1, att1, b1, hbuf);

    // ---- layer 2 ----
    gemm_pair<64><<<1563, 256, 0, stream>>>(hbuf, Wl2, Wr2, xl1, xr1, N_NODES);
    node_fused2<<<12500, 256, 0, stream>>>(rowptr, esrc, xl1, xr1, att2, b2, out_emb);

    // ---- classifier ----
    classifier<<<1563, 256, 0, stream>>>(out_emb, Wc1, bc1, Wc2, bc2, out_logits);
}

// Round 10
// 425.593 us; speedup vs baseline: 23.1720x; 1.0116x over previous
//
#include <hip/hip_runtime.h>
#include <hip/hip_bf16.h>
#include <cfloat>

#define N_NODES 50000
#define N_EDGES 800000
#define E_TOT   850000   /* edges + self-loops */
#define NEG_SLOPE 0.2f
#define SM_EPS 1e-16f
#define SCAN_B 196       /* ceil(50000/256) */

__device__ __forceinline__ float lrelu(float v) { return v > 0.0f ? v : NEG_SLOPE * v; }

// ---- CSR build -------------------------------------------------------------
// Layout detect (per block): int64 edge_index has all odd 32-bit words zero
// (ids < 50000); int32 layout has random src ids there. 256 probes -> exact.

// One atomic pass: histogram + per-edge rank (r = old count). rank16 written
// sequentially; scatter pass then needs NO atomics.
__global__ void count_deg(const int* __restrict__ ei, int* __restrict__ deg,
                          unsigned short* __restrict__ rank16) {
    int nz = __syncthreads_or(ei[2 * threadIdx.x + 1]);   // 0 => int64 layout
    int i = blockIdx.x * blockDim.x + threadIdx.x;        // edge-pair index
    if (2 * i >= N_EDGES) return;
    bool has2 = (2 * i + 1 < N_EDGES);
    int d0, d1 = 0;
    if (nz) {  // int32: [src[E], dst[E]]
        int2 dp = *(const int2*)(ei + N_EDGES + 2 * i);
        d0 = dp.x; d1 = dp.y;
    } else {   // int64: lo words at even indices
        int4 dp = *(const int4*)(ei + 2 * N_EDGES + 4 * i);
        d0 = dp.x; d1 = dp.z;
    }
    unsigned short r0 = (unsigned short)atomicAdd(&deg[d0], 1);
    unsigned short r1 = 0;
    if (has2) r1 = (unsigned short)atomicAdd(&deg[d1], 1);
    // paired sequential store (one dword per thread)
    *(unsigned int*)(rank16 + 2 * i) = (unsigned int)r0 | ((unsigned int)r1 << 16);
}

// blocked exclusive scan; +1 per node folds in the self-loop
__global__ void scan_local(const int* __restrict__ deg, int* __restrict__ rowptr,
                           int* __restrict__ bsum) {
    __shared__ int sh[256];
    int b = blockIdx.x, t = threadIdx.x, i = b * 256 + t;
    int v = (i < N_NODES) ? deg[i] + 1 : 0;
    sh[t] = v;
    __syncthreads();
    int val = v;
    for (int off = 1; off < 256; off <<= 1) {
        int add = (t >= off) ? sh[t - off] : 0;
        __syncthreads();
        val += add; sh[t] = val;
        __syncthreads();
    }
    if (i < N_NODES) rowptr[i] = val - v;
    if (t == 255) bsum[b] = val;
}

// add block offsets (local tree-sum over preceding block sums);
// write self-loop into slot 0 of each node's segment
__global__ void scan_add(int* __restrict__ rowptr, const int* __restrict__ bsum,
                         int* __restrict__ esrc) {
    __shared__ int sh[256];
    int b = blockIdx.x, t = threadIdx.x;
    sh[t] = (t < b && t < SCAN_B) ? bsum[t] : 0;
    __syncthreads();
    #pragma unroll
    for (int off = 128; off; off >>= 1) {
        if (t < off) sh[t] += sh[t + off];
        __syncthreads();
    }
    int offset = sh[0];
    int i = b * 256 + t;
    if (i < N_NODES) {
        int rp = rowptr[i] + offset;
        rowptr[i] = rp;
        esrc[rp] = i;       // self-loop first
    }
    if (i == 0) rowptr[N_NODES] = E_TOT;
}

// no atomics: position = rowptr[dst] + 1 + rank
__global__ void scatter_edges(const int* __restrict__ ei, const int* __restrict__ rowptr,
                              const unsigned short* __restrict__ rank16,
                              int* __restrict__ esrc) {
    int nz = __syncthreads_or(ei[2 * threadIdx.x + 1]);
    int i = blockIdx.x * blockDim.x + threadIdx.x;
    if (2 * i >= N_EDGES) return;
    bool has2 = (2 * i + 1 < N_EDGES);
    int s0, d0, s1 = 0, d1 = 0;
    if (nz) {
        int2 sp = *(const int2*)(ei + 2 * i);
        int2 dp = *(const int2*)(ei + N_EDGES + 2 * i);
        s0 = sp.x; s1 = sp.y; d0 = dp.x; d1 = dp.y;
    } else {
        int4 sp = *(const int4*)(ei + 4 * i);
        int4 dp = *(const int4*)(ei + 2 * N_EDGES + 4 * i);
        s0 = sp.x; s1 = sp.z; d0 = dp.x; d1 = dp.z;
    }
    unsigned int rr = *(const unsigned int*)(rank16 + 2 * i);
    esrc[rowptr[d0] + 1 + (int)(rr & 0xffffu)] = s0;
    if (has2) esrc[rowptr[d1] + 1 + (int)(rr >> 16)] = s1;
}

// ---------------- GEMM pair: C0 = A@B0, C1 = A@B1 ; A[M,128], B[128,N] ----------------
// 256 threads, 64 rows/block, register-double-buffered k-loop.
// Thread tile: RPT rows x 4 cols (RPT = 16 for N=128, 8 for N=64).
template<int N>
__global__ __launch_bounds__(256)
void gemm_pair(const float* __restrict__ A, const float* __restrict__ B0,
               const float* __restrict__ B1, float* __restrict__ C0,
               float* __restrict__ C1, int M) {
    constexpr int ROWS = 64;
    constexpr int JQ  = N / 4;            // col quads per matrix
    constexpr int RG  = 128 / JQ;         // row groups (threads = JQ*RG*2 = 256)
    constexpr int RPT = ROWS / RG;        // rows per thread
    __shared__ float aT[128][ROWS + 4];
    int t = threadIdx.x;
    int jq    = t % JQ;
    int rg    = (t / JQ) % RG;
    int which = t / 128;
    const float* B = which ? B1 : B0;
    float*       C = which ? C1 : C0;
    int row0 = blockIdx.x * ROWS;
    for (int i = t; i < ROWS * 128; i += 256) {
        int r = i >> 7, kk = i & 127;
        int row = row0 + r;
        aT[kk][r] = (row < M) ? A[(size_t)row * 128 + kk] : 0.0f;
    }
    __syncthreads();
    float acc[RPT][4];
    #pragma unroll
    for (int r = 0; r < RPT; ++r)
        #pragma unroll
        for (int c = 0; c < 4; ++c) acc[r][c] = 0.0f;
    const float* Bp = B + jq * 4;
    const int rbase = rg * RPT;
    float4 b4 = *(const float4*)(Bp);
    float av[RPT];
    #pragma unroll
    for (int q = 0; q < RPT; q += 4)
        *(float4*)&av[q] = *(const float4*)&aT[0][rbase + q];
    for (int k = 0; k < 127; ++k) {
        float4 b4n = *(const float4*)(Bp + (size_t)(k + 1) * N);
        float avn[RPT];
        #pragma unroll
        for (int q = 0; q < RPT; q += 4)
            *(float4*)&avn[q] = *(const float4*)&aT[k + 1][rbase + q];
        #pragma unroll
        for (int r = 0; r < RPT; ++r) {
            acc[r][0] += av[r] * b4.x;
            acc[r][1] += av[r] * b4.y;
            acc[r][2] += av[r] * b4.z;
            acc[r][3] += av[r] * b4.w;
        }
        b4 = b4n;
        #pragma unroll
        for (int r = 0; r < RPT; ++r) av[r] = avn[r];
    }
    #pragma unroll
    for (int r = 0; r < RPT; ++r) {
        acc[r][0] += av[r] * b4.x;
        acc[r][1] += av[r] * b4.y;
        acc[r][2] += av[r] * b4.z;
        acc[r][3] += av[r] * b4.w;
    }
    #pragma unroll
    for (int r = 0; r < RPT; ++r) {
        int row = row0 + rbase + r;
        if (row < M) {
            float4 o; o.x = acc[r][0]; o.y = acc[r][1]; o.z = acc[r][2]; o.w = acc[r][3];
            *(float4*)(C + (size_t)row * N + jq * 4) = o;
        }
    }
}

// ---------------- Layer 1 (H=8, C=16) ----------------
// Node per wave; wave = 4 edge-slots x 16 lanes; lane holds 8 channels (2xfloat4).
__global__ __launch_bounds__(256)
void node_fused1(const int* __restrict__ rowptr, const int* __restrict__ esrc,
                 const float* __restrict__ xl, const float* __restrict__ xr,
                 const float* __restrict__ att, const float* __restrict__ b1,
                 float* __restrict__ hout) {
    int wave = threadIdx.x >> 6;
    int lane = threadIdx.x & 63;
    int n = blockIdx.x * 4 + wave;            // grid = 12500 exact
    int slot = lane >> 4;                     // 0..3
    int l = lane & 15;                        // channels 8l..8l+7
    int beg = rowptr[n], end = rowptr[n + 1];
    const float* xrp = xr + (size_t)n * 128 + 8 * l;
    float4 xra = *(const float4*)(xrp);
    float4 xrb = *(const float4*)(xrp + 4);
    float4 ata = *(const float4*)(att + 8 * l);
    float4 atb = *(const float4*)(att + 8 * l + 4);
    float den = 0.0f;
    float4 aa = {0, 0, 0, 0}, ab = {0, 0, 0, 0};

    auto body = [&](int k) {
        int s = esrc[k];
        const float* xp = xl + (size_t)s * 128 + 8 * l;
        float4 xa = *(const float4*)(xp);
        float4 xb = *(const float4*)(xp + 4);
        float v = ata.x * lrelu(xa.x + xra.x) + ata.y * lrelu(xa.y + xra.y)
                + ata.z * lrelu(xa.z + xra.z) + ata.w * lrelu(xa.w + xra.w)
                + atb.x * lrelu(xb.x + xrb.x) + atb.y * lrelu(xb.y + xrb.y)
                + atb.z * lrelu(xb.z + xrb.z) + atb.w * lrelu(xb.w + xrb.w);
        v += __shfl_xor(v, 1);                // combine the head's two lanes
        float p = __expf(v);
        den += p;
        aa.x += p * xa.x; aa.y += p * xa.y; aa.z += p * xa.z; aa.w += p * xa.w;
        ab.x += p * xb.x; ab.y += p * xb.y; ab.z += p * xb.z; ab.w += p * xb.w;
    };
    int k = beg + slot;
    for (; k + 4 < end; k += 8) { body(k); body(k + 4); }
    if (k < end) body(k);

    // merge 4 slots
    #pragma unroll
    for (int off = 16; off < 64; off <<= 1) {
        aa.x += __shfl_xor(aa.x, off); aa.y += __shfl_xor(aa.y, off);
        aa.z += __shfl_xor(aa.z, off); aa.w += __shfl_xor(aa.w, off);
        ab.x += __shfl_xor(ab.x, off); ab.y += __shfl_xor(ab.y, off);
        ab.z += __shfl_xor(ab.z, off); ab.w += __shfl_xor(ab.w, off);
        den   += __shfl_xor(den, off);
    }
    if (slot == 0) {
        float inv = 1.0f / (den + SM_EPS);
        float4 b4a = *(const float4*)(b1 + 8 * l);
        float4 b4b = *(const float4*)(b1 + 8 * l + 4);
        float4 oa, ob;
        oa.x = fmaxf(aa.x * inv + b4a.x, 0.0f);
        oa.y = fmaxf(aa.y * inv + b4a.y, 0.0f);
        oa.z = fmaxf(aa.z * inv + b4a.z, 0.0f);
        oa.w = fmaxf(aa.w * inv + b4a.w, 0.0f);
        ob.x = fmaxf(ab.x * inv + b4b.x, 0.0f);
        ob.y = fmaxf(ab.y * inv + b4b.y, 0.0f);
        ob.z = fmaxf(ab.z * inv + b4b.z, 0.0f);
        ob.w = fmaxf(ab.w * inv + b4b.w, 0.0f);
        float* op = hout + (size_t)n * 128 + 8 * l;
        *(float4*)(op)     = oa;
        *(float4*)(op + 4) = ob;
    }
}

// ---------------- Layer 2 (H=1, C=64) ----------------
// Node per wave; wave = 8 edge-slots x 8 lanes; lane holds 8 channels.
__global__ __launch_bounds__(256)
void node_fused2(const int* __restrict__ rowptr, const int* __restrict__ esrc,
                 const float* __restrict__ xl, const float* __restrict__ xr,
                 const float* __restrict__ att, const float* __restrict__ b2v,
                 float* __restrict__ out_emb) {
    int wave = threadIdx.x >> 6;
    int lane = threadIdx.x & 63;
    int n = blockIdx.x * 4 + wave;
    int slot = lane >> 3;                     // 0..7
    int l = lane & 7;                         // channels 8l..8l+7
    int beg = rowptr[n], end = rowptr[n + 1];
    const float* xrp = xr + (size_t)n * 64 + 8 * l;
    float4 xra = *(const float4*)(xrp);
    float4 xrb = *(const float4*)(xrp + 4);
    float4 ata = *(const float4*)(att + 8 * l);
    float4 atb = *(const float4*)(att + 8 * l + 4);
    float den = 0.0f;
    float4 aa = {0, 0, 0, 0}, ab = {0, 0, 0, 0};

    auto body = [&](int k) {
        int s = esrc[k];
        const float* xp = xl + (size_t)s * 64 + 8 * l;
        float4 xa = *(const float4*)(xp);
        float4 xb = *(const float4*)(xp + 4);
        float v = ata.x * lrelu(xa.x + xra.x) + ata.y * lrelu(xa.y + xra.y)
                + ata.z * lrelu(xa.z + xra.z) + ata.w * lrelu(xa.w + xra.w)
                + atb.x * lrelu(xb.x + xrb.x) + atb.y * lrelu(xb.y + xrb.y)
                + atb.z * lrelu(xb.z + xrb.z) + atb.w * lrelu(xb.w + xrb.w);
        v += __shfl_xor(v, 1);
        v += __shfl_xor(v, 2);
        v += __shfl_xor(v, 4);
        float p = __expf(v);
        den += p;
        aa.x += p * xa.x; aa.y += p * xa.y; aa.z += p * xa.z; aa.w += p * xa.w;
        ab.x += p * xb.x; ab.y += p * xb.y; ab.z += p * xb.z; ab.w += p * xb.w;
    };
    int k = beg + slot;
    for (; k + 8 < end; k += 16) { body(k); body(k + 8); }
    if (k < end) body(k);

    // merge 8 slots
    #pragma unroll
    for (int off = 8; off < 64; off <<= 1) {
        aa.x += __shfl_xor(aa.x, off); aa.y += __shfl_xor(aa.y, off);
        aa.z += __shfl_xor(aa.z, off); aa.w += __shfl_xor(aa.w, off);
        ab.x += __shfl_xor(ab.x, off); ab.y += __shfl_xor(ab.y, off);
        ab.z += __shfl_xor(ab.z, off); ab.w += __shfl_xor(ab.w, off);
        den   += __shfl_xor(den, off);
    }
    if (slot == 0) {
        float inv = 1.0f / (den + SM_EPS);
        float4 b4a = *(const float4*)(b2v + 8 * l);
        float4 b4b = *(const float4*)(b2v + 8 * l + 4);
        float4 ea, eb;
        ea.x = aa.x * inv + b4a.x; ea.y = aa.y * inv + b4a.y;
        ea.z = aa.z * inv + b4a.z; ea.w = aa.w * inv + b4a.w;
        eb.x = ab.x * inv + b4b.x; eb.y = ab.y * inv + b4b.y;
        eb.z = ab.z * inv + b4b.z; eb.w = ab.w * inv + b4b.w;
        float* op = out_emb + (size_t)n * 64 + 8 * l;
        *(float4*)(op)     = ea;
        *(float4*)(op + 4) = eb;
    }
}

// ---------------- Classifier: LDS-tiled ----------------
#define CLS_NODES 32
__global__ __launch_bounds__(256)
void classifier(const float* __restrict__ emb, const float* __restrict__ Wc1,
                const float* __restrict__ bc1, const float* __restrict__ Wc2,
                const float* __restrict__ bc2, float* __restrict__ out_logits) {
    __shared__ float w1[64 * 128];            // 32 KB
    __shared__ float eS[CLS_NODES][64];       // 8 KB
    __shared__ float tS[CLS_NODES][132];      // pad 132 breaks phase-C conflicts
    int t = threadIdx.x;
    int n0 = blockIdx.x * CLS_NODES;
    for (int i = t; i < 64 * 128 / 4; i += 256)
        ((float4*)w1)[i] = ((const float4*)Wc1)[i];
    for (int i = t; i < CLS_NODES * 64 / 4; i += 256) {
        size_t off = (size_t)n0 * 64 + i * 4;
        float4 v = {0, 0, 0, 0};
        if (off + 3 < (size_t)N_NODES * 64) v = *(const float4*)(emb + off);
        ((float4*)eS)[i] = v;
    }
    __syncthreads();
    int jj = t & 127, half = t >> 7;
    for (int nn = half; nn < CLS_NODES; nn += 2) {
        float a0 = 0, a1 = 0, a2 = 0, a3 = 0;
        #pragma unroll
        for (int k = 0; k < 64; k += 4) {
            a0 += eS[nn][k]     * w1[(k)     * 128 + jj];
            a1 += eS[nn][k + 1] * w1[(k + 1) * 128 + jj];
            a2 += eS[nn][k + 2] * w1[(k + 2) * 128 + jj];
            a3 += eS[nn][k + 3] * w1[(k + 3) * 128 + jj];
        }
        tS[nn][jj] = fmaxf(bc1[jj] + (a0 + a1) + (a2 + a3), 0.0f);
    }
    __syncthreads();
    int node = t >> 3, seg = t & 7;
    float v0 = 0, v1 = 0;
    #pragma unroll
    for (int c = 0; c < 16; ++c) {
        float tv = tS[node][seg * 16 + c];
        v0 += tv * Wc2[2 * (seg * 16 + c)];
        v1 += tv * Wc2[2 * (seg * 16 + c) + 1];
    }
    v0 += __shfl_xor(v0, 1); v1 += __shfl_xor(v1, 1);
    v0 += __shfl_xor(v0, 2); v1 += __shfl_xor(v1, 2);
    v0 += __shfl_xor(v0, 4); v1 += __shfl_xor(v1, 4);
    int n = n0 + node;
    if (seg == 0 && n < N_NODES) {
        out_logits[(size_t)n * 2 + 0] = v0 + bc2[0];
        out_logits[(size_t)n * 2 + 1] = v1 + bc2[1];
    }
}

extern "C" void kernel_launch(void* const* d_in, const int* in_sizes, int n_in,
                              void* d_out, int out_size, void* d_ws, size_t ws_size,
                              hipStream_t stream) {
    const float* x    = (const float*)d_in[0];
    const int*   ei   = (const int*)d_in[1];
    const float* Wl1  = (const float*)d_in[3];
    const float* Wr1  = (const float*)d_in[4];
    const float* att1 = (const float*)d_in[5];
    const float* b1   = (const float*)d_in[6];
    const float* Wl2  = (const float*)d_in[7];
    const float* Wr2  = (const float*)d_in[8];
    const float* att2 = (const float*)d_in[9];
    const float* b2   = (const float*)d_in[10];
    const float* Wc1  = (const float*)d_in[15];
    const float* bc1  = (const float*)d_in[16];
    const float* Wc2  = (const float*)d_in[17];
    const float* bc2  = (const float*)d_in[18];

    float* ws = (float*)d_ws;
    int* deg    = (int*)ws;                        //      0 .. 50000 (zeroed by memset)
    int* rowptr = deg + 50000;                     //  50000 .. 100016
    int* esrc   = rowptr + 50016;                  // 100016 .. 950016
    int* bsum   = esrc + 850000;                   // 950016 .. 950272
    unsigned short* rank16 = (unsigned short*)(bsum + 256);  // 800000 u16 -> 400000 ints
    float* xl1  = ws + 1400448;                    // 6.40M (layer2 xl2 in first 3.2M)
    float* xr1  = ws + 7800448;                    // 6.40M (layer2 xr2)
    float* hbuf = ws + 14200448;                   // 6.40M -> ends 20.6M words ≈ 82 MB

    float* out_emb    = (float*)d_out;
    float* out_logits = out_emb + (size_t)N_NODES * 64;

    // ---- CSR build ----
    hipMemsetAsync(deg, 0, 50000 * sizeof(int), stream);
    count_deg<<<1563, 256, 0, stream>>>(ei, deg, rank16);
    scan_local<<<SCAN_B, 256, 0, stream>>>(deg, rowptr, bsum);
    scan_add<<<SCAN_B, 256, 0, stream>>>(rowptr, bsum, esrc);
    scatter_edges<<<1563, 256, 0, stream>>>(ei, rowptr, rank16, esrc);

    // ---- layer 1 ----
    gemm_pair<128><<<782, 256, 0, stream>>>(x, Wl1, Wr1, xl1, xr1, N_NODES);
    node_fused1<<<12500, 256, 0, stream>>>(rowptr, esrc, xl1, xr1, att1, b1, hbuf);

    // ---- layer 2 ----
    gemm_pair<64><<<782, 256, 0, stream>>>(hbuf, Wl2, Wr2, xl1, xr1, N_NODES);
    node_fused2<<<12500, 256, 0, stream>>>(rowptr, esrc, xl1, xr1, att2, b2, out_emb);

    // ---- classifier ----
    classifier<<<1563, 256, 0, stream>>>(out_emb, Wc1, bc1, Wc2, bc2, out_logits);
}

// Round 11
// 395.459 us; speedup vs baseline: 24.9377x; 1.0762x over previous
//
#include <hip/hip_runtime.h>
#include <hip/hip_bf16.h>
#include <cfloat>

#define N_NODES 50000
#define N_EDGES 800000
#define E_TOT   850000   /* edges + self-loops */
#define NEG_SLOPE 0.2f
#define SM_EPS 1e-16f
#define SCAN_B 196       /* ceil(50000/256) */

__device__ __forceinline__ float lrelu(float v) { return v > 0.0f ? v : NEG_SLOPE * v; }

// ---- CSR build -------------------------------------------------------------
// Layout detect (per block): int64 edge_index has all odd 32-bit words zero
// (ids < 50000); int32 layout has random src ids there. 256 probes -> exact.

// One atomic pass: histogram + per-edge rank (r = old count). rank16 written
// sequentially; scatter pass then needs NO atomics.
__global__ void count_deg(const int* __restrict__ ei, int* __restrict__ deg,
                          unsigned short* __restrict__ rank16) {
    int nz = __syncthreads_or(ei[2 * threadIdx.x + 1]);   // 0 => int64 layout
    int i = blockIdx.x * blockDim.x + threadIdx.x;        // edge-pair index
    if (2 * i >= N_EDGES) return;
    bool has2 = (2 * i + 1 < N_EDGES);
    int d0, d1 = 0;
    if (nz) {  // int32: [src[E], dst[E]]
        int2 dp = *(const int2*)(ei + N_EDGES + 2 * i);
        d0 = dp.x; d1 = dp.y;
    } else {   // int64: lo words at even indices
        int4 dp = *(const int4*)(ei + 2 * N_EDGES + 4 * i);
        d0 = dp.x; d1 = dp.z;
    }
    unsigned short r0 = (unsigned short)atomicAdd(&deg[d0], 1);
    unsigned short r1 = 0;
    if (has2) r1 = (unsigned short)atomicAdd(&deg[d1], 1);
    *(unsigned int*)(rank16 + 2 * i) = (unsigned int)r0 | ((unsigned int)r1 << 16);
}

// blocked exclusive scan; +1 per node folds in the self-loop
__global__ void scan_local(const int* __restrict__ deg, int* __restrict__ rowptr,
                           int* __restrict__ bsum) {
    __shared__ int sh[256];
    int b = blockIdx.x, t = threadIdx.x, i = b * 256 + t;
    int v = (i < N_NODES) ? deg[i] + 1 : 0;
    sh[t] = v;
    __syncthreads();
    int val = v;
    for (int off = 1; off < 256; off <<= 1) {
        int add = (t >= off) ? sh[t - off] : 0;
        __syncthreads();
        val += add; sh[t] = val;
        __syncthreads();
    }
    if (i < N_NODES) rowptr[i] = val - v;
    if (t == 255) bsum[b] = val;
}

// add block offsets (local tree-sum over preceding block sums);
// write self-loop into slot 0 of each node's segment
__global__ void scan_add(int* __restrict__ rowptr, const int* __restrict__ bsum,
                         int* __restrict__ esrc) {
    __shared__ int sh[256];
    int b = blockIdx.x, t = threadIdx.x;
    sh[t] = (t < b && t < SCAN_B) ? bsum[t] : 0;
    __syncthreads();
    #pragma unroll
    for (int off = 128; off; off >>= 1) {
        if (t < off) sh[t] += sh[t + off];
        __syncthreads();
    }
    int offset = sh[0];
    int i = b * 256 + t;
    if (i < N_NODES) {
        int rp = rowptr[i] + offset;
        rowptr[i] = rp;
        esrc[rp] = i;       // self-loop first
    }
    if (i == 0) rowptr[N_NODES] = E_TOT;
}

// no atomics: position = rowptr[dst] + 1 + rank
__global__ void scatter_edges(const int* __restrict__ ei, const int* __restrict__ rowptr,
                              const unsigned short* __restrict__ rank16,
                              int* __restrict__ esrc) {
    int nz = __syncthreads_or(ei[2 * threadIdx.x + 1]);
    int i = blockIdx.x * blockDim.x + threadIdx.x;
    if (2 * i >= N_EDGES) return;
    bool has2 = (2 * i + 1 < N_EDGES);
    int s0, d0, s1 = 0, d1 = 0;
    if (nz) {
        int2 sp = *(const int2*)(ei + 2 * i);
        int2 dp = *(const int2*)(ei + N_EDGES + 2 * i);
        s0 = sp.x; s1 = sp.y; d0 = dp.x; d1 = dp.y;
    } else {
        int4 sp = *(const int4*)(ei + 4 * i);
        int4 dp = *(const int4*)(ei + 2 * N_EDGES + 4 * i);
        s0 = sp.x; s1 = sp.z; d0 = dp.x; d1 = dp.z;
    }
    unsigned int rr = *(const unsigned int*)(rank16 + 2 * i);
    esrc[rowptr[d0] + 1 + (int)(rr & 0xffffu)] = s0;
    if (has2) esrc[rowptr[d1] + 1 + (int)(rr >> 16)] = s1;
}

// ---------------- GEMM pair: C0 = A@B0, C1 = A@B1 ; A[M,128], B[128,N] ----------------
// 256 threads, 32 rows/block, unroll-2 k-loop with B prefetched TWO k-steps ahead
// (covers ~200-cycle L2 latency). Thread tile: RPT rows x 4 cols.
template<int N>
__global__ __launch_bounds__(256)
void gemm_pair(const float* __restrict__ A, const float* __restrict__ B0,
               const float* __restrict__ B1, float* __restrict__ C0,
               float* __restrict__ C1, int M) {
    constexpr int JQ  = N / 4;          // col quads per matrix
    constexpr int RG  = 128 / JQ;       // row groups (threads = JQ*RG*2 = 256)
    constexpr int RPT = 32 / RG;        // rows per thread (8 for N=128, 4 for N=64)
    __shared__ float aT[128][36];
    int t = threadIdx.x;
    int jq    = t % JQ;
    int rg    = (t / JQ) % RG;
    int which = t / 128;
    const float* B = which ? B1 : B0;
    float*       C = which ? C1 : C0;
    int row0 = blockIdx.x * 32;
    for (int i = t; i < 32 * 128; i += 256) {
        int r = i >> 7, kk = i & 127;
        int row = row0 + r;
        aT[kk][r] = (row < M) ? A[(size_t)row * 128 + kk] : 0.0f;
    }
    __syncthreads();
    float acc[RPT][4];
    #pragma unroll
    for (int r = 0; r < RPT; ++r)
        #pragma unroll
        for (int c = 0; c < 4; ++c) acc[r][c] = 0.0f;
    const float* Bp = B + jq * 4;
    const int rbase = rg * RPT;
    float4 bb0 = *(const float4*)(Bp);
    float4 bb1 = *(const float4*)(Bp + N);
    for (int k = 0; k < 126; k += 2) {
        float4 bn0 = *(const float4*)(Bp + (size_t)(k + 2) * N);
        float4 bn1 = *(const float4*)(Bp + (size_t)(k + 3) * N);
        float av0[RPT], av1[RPT];
        #pragma unroll
        for (int q = 0; q < RPT; q += 4) {
            *(float4*)&av0[q] = *(const float4*)&aT[k][rbase + q];
            *(float4*)&av1[q] = *(const float4*)&aT[k + 1][rbase + q];
        }
        #pragma unroll
        for (int r = 0; r < RPT; ++r) {
            acc[r][0] += av0[r] * bb0.x; acc[r][1] += av0[r] * bb0.y;
            acc[r][2] += av0[r] * bb0.z; acc[r][3] += av0[r] * bb0.w;
        }
        #pragma unroll
        for (int r = 0; r < RPT; ++r) {
            acc[r][0] += av1[r] * bb1.x; acc[r][1] += av1[r] * bb1.y;
            acc[r][2] += av1[r] * bb1.z; acc[r][3] += av1[r] * bb1.w;
        }
        bb0 = bn0; bb1 = bn1;
    }
    {   // k = 126, 127
        float av0[RPT], av1[RPT];
        #pragma unroll
        for (int q = 0; q < RPT; q += 4) {
            *(float4*)&av0[q] = *(const float4*)&aT[126][rbase + q];
            *(float4*)&av1[q] = *(const float4*)&aT[127][rbase + q];
        }
        #pragma unroll
        for (int r = 0; r < RPT; ++r) {
            acc[r][0] += av0[r] * bb0.x; acc[r][1] += av0[r] * bb0.y;
            acc[r][2] += av0[r] * bb0.z; acc[r][3] += av0[r] * bb0.w;
        }
        #pragma unroll
        for (int r = 0; r < RPT; ++r) {
            acc[r][0] += av1[r] * bb1.x; acc[r][1] += av1[r] * bb1.y;
            acc[r][2] += av1[r] * bb1.z; acc[r][3] += av1[r] * bb1.w;
        }
    }
    #pragma unroll
    for (int r = 0; r < RPT; ++r) {
        int row = row0 + rbase + r;
        if (row < M) {
            float4 o; o.x = acc[r][0]; o.y = acc[r][1]; o.z = acc[r][2]; o.w = acc[r][3];
            *(float4*)(C + (size_t)row * N + jq * 4) = o;
        }
    }
}

// ---------------- Layer 1 (H=8, C=16) ----------------
// Node per wave; wave = 4 edge-slots x 16 lanes; lane holds 8 channels (2xfloat4).
__global__ __launch_bounds__(256)
void node_fused1(const int* __restrict__ rowptr, const int* __restrict__ esrc,
                 const float* __restrict__ xl, const float* __restrict__ xr,
                 const float* __restrict__ att, const float* __restrict__ b1,
                 float* __restrict__ hout) {
    int wave = threadIdx.x >> 6;
    int lane = threadIdx.x & 63;
    int n = blockIdx.x * 4 + wave;            // grid = 12500 exact
    int slot = lane >> 4;                     // 0..3
    int l = lane & 15;                        // channels 8l..8l+7
    int beg = rowptr[n], end = rowptr[n + 1];
    const float* xrp = xr + (size_t)n * 128 + 8 * l;
    float4 xra = *(const float4*)(xrp);
    float4 xrb = *(const float4*)(xrp + 4);
    float4 ata = *(const float4*)(att + 8 * l);
    float4 atb = *(const float4*)(att + 8 * l + 4);
    float den = 0.0f;
    float4 aa = {0, 0, 0, 0}, ab = {0, 0, 0, 0};

    auto body = [&](int k) {
        int s = esrc[k];
        const float* xp = xl + (size_t)s * 128 + 8 * l;
        float4 xa = *(const float4*)(xp);
        float4 xb = *(const float4*)(xp + 4);
        float v = ata.x * lrelu(xa.x + xra.x) + ata.y * lrelu(xa.y + xra.y)
                + ata.z * lrelu(xa.z + xra.z) + ata.w * lrelu(xa.w + xra.w)
                + atb.x * lrelu(xb.x + xrb.x) + atb.y * lrelu(xb.y + xrb.y)
                + atb.z * lrelu(xb.z + xrb.z) + atb.w * lrelu(xb.w + xrb.w);
        v += __shfl_xor(v, 1);                // combine the head's two lanes
        float p = __expf(v);
        den += p;
        aa.x += p * xa.x; aa.y += p * xa.y; aa.z += p * xa.z; aa.w += p * xa.w;
        ab.x += p * xb.x; ab.y += p * xb.y; ab.z += p * xb.z; ab.w += p * xb.w;
    };
    int k = beg + slot;
    for (; k + 4 < end; k += 8) { body(k); body(k + 4); }
    if (k < end) body(k);

    // merge 4 slots
    #pragma unroll
    for (int off = 16; off < 64; off <<= 1) {
        aa.x += __shfl_xor(aa.x, off); aa.y += __shfl_xor(aa.y, off);
        aa.z += __shfl_xor(aa.z, off); aa.w += __shfl_xor(aa.w, off);
        ab.x += __shfl_xor(ab.x, off); ab.y += __shfl_xor(ab.y, off);
        ab.z += __shfl_xor(ab.z, off); ab.w += __shfl_xor(ab.w, off);
        den   += __shfl_xor(den, off);
    }
    if (slot == 0) {
        float inv = 1.0f / (den + SM_EPS);
        float4 b4a = *(const float4*)(b1 + 8 * l);
        float4 b4b = *(const float4*)(b1 + 8 * l + 4);
        float4 oa, ob;
        oa.x = fmaxf(aa.x * inv + b4a.x, 0.0f);
        oa.y = fmaxf(aa.y * inv + b4a.y, 0.0f);
        oa.z = fmaxf(aa.z * inv + b4a.z, 0.0f);
        oa.w = fmaxf(aa.w * inv + b4a.w, 0.0f);
        ob.x = fmaxf(ab.x * inv + b4b.x, 0.0f);
        ob.y = fmaxf(ab.y * inv + b4b.y, 0.0f);
        ob.z = fmaxf(ab.z * inv + b4b.z, 0.0f);
        ob.w = fmaxf(ab.w * inv + b4b.w, 0.0f);
        float* op = hout + (size_t)n * 128 + 8 * l;
        *(float4*)(op)     = oa;
        *(float4*)(op + 4) = ob;
    }
}

// ---------------- Layer 2 (H=1, C=64) ----------------
// Node per wave; wave = 8 edge-slots x 8 lanes; lane holds 8 channels.
__global__ __launch_bounds__(256)
void node_fused2(const int* __restrict__ rowptr, const int* __restrict__ esrc,
                 const float* __restrict__ xl, const float* __restrict__ xr,
                 const float* __restrict__ att, const float* __restrict__ b2v,
                 float* __restrict__ out_emb) {
    int wave = threadIdx.x >> 6;
    int lane = threadIdx.x & 63;
    int n = blockIdx.x * 4 + wave;
    int slot = lane >> 3;                     // 0..7
    int l = lane & 7;                         // channels 8l..8l+7
    int beg = rowptr[n], end = rowptr[n + 1];
    const float* xrp = xr + (size_t)n * 64 + 8 * l;
    float4 xra = *(const float4*)(xrp);
    float4 xrb = *(const float4*)(xrp + 4);
    float4 ata = *(const float4*)(att + 8 * l);
    float4 atb = *(const float4*)(att + 8 * l + 4);
    float den = 0.0f;
    float4 aa = {0, 0, 0, 0}, ab = {0, 0, 0, 0};

    auto body = [&](int k) {
        int s = esrc[k];
        const float* xp = xl + (size_t)s * 64 + 8 * l;
        float4 xa = *(const float4*)(xp);
        float4 xb = *(const float4*)(xp + 4);
        float v = ata.x * lrelu(xa.x + xra.x) + ata.y * lrelu(xa.y + xra.y)
                + ata.z * lrelu(xa.z + xra.z) + ata.w * lrelu(xa.w + xra.w)
                + atb.x * lrelu(xb.x + xrb.x) + atb.y * lrelu(xb.y + xrb.y)
                + atb.z * lrelu(xb.z + xrb.z) + atb.w * lrelu(xb.w + xrb.w);
        v += __shfl_xor(v, 1);
        v += __shfl_xor(v, 2);
        v += __shfl_xor(v, 4);
        float p = __expf(v);
        den += p;
        aa.x += p * xa.x; aa.y += p * xa.y; aa.z += p * xa.z; aa.w += p * xa.w;
        ab.x += p * xb.x; ab.y += p * xb.y; ab.z += p * xb.z; ab.w += p * xb.w;
    };
    int k = beg + slot;
    for (; k + 8 < end; k += 16) { body(k); body(k + 8); }
    if (k < end) body(k);

    // merge 8 slots
    #pragma unroll
    for (int off = 8; off < 64; off <<= 1) {
        aa.x += __shfl_xor(aa.x, off); aa.y += __shfl_xor(aa.y, off);
        aa.z += __shfl_xor(aa.z, off); aa.w += __shfl_xor(aa.w, off);
        ab.x += __shfl_xor(ab.x, off); ab.y += __shfl_xor(ab.y, off);
        ab.z += __shfl_xor(ab.z, off); ab.w += __shfl_xor(ab.w, off);
        den   += __shfl_xor(den, off);
    }
    if (slot == 0) {
        float inv = 1.0f / (den + SM_EPS);
        float4 b4a = *(const float4*)(b2v + 8 * l);
        float4 b4b = *(const float4*)(b2v + 8 * l + 4);
        float4 ea, eb;
        ea.x = aa.x * inv + b4a.x; ea.y = aa.y * inv + b4a.y;
        ea.z = aa.z * inv + b4a.z; ea.w = aa.w * inv + b4a.w;
        eb.x = ab.x * inv + b4b.x; eb.y = ab.y * inv + b4b.y;
        eb.z = ab.z * inv + b4b.z; eb.w = ab.w * inv + b4b.w;
        float* op = out_emb + (size_t)n * 64 + 8 * l;
        *(float4*)(op)     = ea;
        *(float4*)(op + 4) = eb;
    }
}

// ---------------- Classifier: LDS-tiled ----------------
#define CLS_NODES 32
__global__ __launch_bounds__(256)
void classifier(const float* __restrict__ emb, const float* __restrict__ Wc1,
                const float* __restrict__ bc1, const float* __restrict__ Wc2,
                const float* __restrict__ bc2, float* __restrict__ out_logits) {
    __shared__ float w1[64 * 128];            // 32 KB
    __shared__ float eS[CLS_NODES][64];       // 8 KB
    __shared__ float tS[CLS_NODES][132];      // pad 132 breaks phase-C conflicts
    int t = threadIdx.x;
    int n0 = blockIdx.x * CLS_NODES;
    for (int i = t; i < 64 * 128 / 4; i += 256)
        ((float4*)w1)[i] = ((const float4*)Wc1)[i];
    for (int i = t; i < CLS_NODES * 64 / 4; i += 256) {
        size_t off = (size_t)n0 * 64 + i * 4;
        float4 v = {0, 0, 0, 0};
        if (off + 3 < (size_t)N_NODES * 64) v = *(const float4*)(emb + off);
        ((float4*)eS)[i] = v;
    }
    __syncthreads();
    int jj = t & 127, half = t >> 7;
    for (int nn = half; nn < CLS_NODES; nn += 2) {
        float a0 = 0, a1 = 0, a2 = 0, a3 = 0;
        #pragma unroll
        for (int k = 0; k < 64; k += 4) {
            a0 += eS[nn][k]     * w1[(k)     * 128 + jj];
            a1 += eS[nn][k + 1] * w1[(k + 1) * 128 + jj];
            a2 += eS[nn][k + 2] * w1[(k + 2) * 128 + jj];
            a3 += eS[nn][k + 3] * w1[(k + 3) * 128 + jj];
        }
        tS[nn][jj] = fmaxf(bc1[jj] + (a0 + a1) + (a2 + a3), 0.0f);
    }
    __syncthreads();
    int node = t >> 3, seg = t & 7;
    float v0 = 0, v1 = 0;
    #pragma unroll
    for (int c = 0; c < 16; ++c) {
        float tv = tS[node][seg * 16 + c];
        v0 += tv * Wc2[2 * (seg * 16 + c)];
        v1 += tv * Wc2[2 * (seg * 16 + c) + 1];
    }
    v0 += __shfl_xor(v0, 1); v1 += __shfl_xor(v1, 1);
    v0 += __shfl_xor(v0, 2); v1 += __shfl_xor(v1, 2);
    v0 += __shfl_xor(v0, 4); v1 += __shfl_xor(v1, 4);
    int n = n0 + node;
    if (seg == 0 && n < N_NODES) {
        out_logits[(size_t)n * 2 + 0] = v0 + bc2[0];
        out_logits[(size_t)n * 2 + 1] = v1 + bc2[1];
    }
}

extern "C" void kernel_launch(void* const* d_in, const int* in_sizes, int n_in,
                              void* d_out, int out_size, void* d_ws, size_t ws_size,
                              hipStream_t stream) {
    const float* x    = (const float*)d_in[0];
    const int*   ei   = (const int*)d_in[1];
    const float* Wl1  = (const float*)d_in[3];
    const float* Wr1  = (const float*)d_in[4];
    const float* att1 = (const float*)d_in[5];
    const float* b1   = (const float*)d_in[6];
    const float* Wl2  = (const float*)d_in[7];
    const float* Wr2  = (const float*)d_in[8];
    const float* att2 = (const float*)d_in[9];
    const float* b2   = (const float*)d_in[10];
    const float* Wc1  = (const float*)d_in[15];
    const float* bc1  = (const float*)d_in[16];
    const float* Wc2  = (const float*)d_in[17];
    const float* bc2  = (const float*)d_in[18];

    float* ws = (float*)d_ws;
    int* deg    = (int*)ws;                        //      0 .. 50000 (zeroed by memset)
    int* rowptr = deg + 50000;                     //  50000 .. 100016
    int* esrc   = rowptr + 50016;                  // 100016 .. 950016
    int* bsum   = esrc + 850000;                   // 950016 .. 950272
    unsigned short* rank16 = (unsigned short*)(bsum + 256);  // 800000 u16 -> 400000 ints
    float* xl1  = ws + 1400448;                    // 6.40M (layer2 xl2 in first 3.2M)
    float* xr1  = ws + 7800448;                    // 6.40M (layer2 xr2)
    float* hbuf = ws + 14200448;                   // 6.40M -> ends 20.6M words ≈ 82 MB

    float* out_emb    = (float*)d_out;
    float* out_logits = out_emb + (size_t)N_NODES * 64;

    // ---- CSR build ----
    hipMemsetAsync(deg, 0, 50000 * sizeof(int), stream);
    count_deg<<<1563, 256, 0, stream>>>(ei, deg, rank16);
    scan_local<<<SCAN_B, 256, 0, stream>>>(deg, rowptr, bsum);
    scan_add<<<SCAN_B, 256, 0, stream>>>(rowptr, bsum, esrc);
    scatter_edges<<<1563, 256, 0, stream>>>(ei, rowptr, rank16, esrc);

    // ---- layer 1 ----
    gemm_pair<128><<<1563, 256, 0, stream>>>(x, Wl1, Wr1, xl1, xr1, N_NODES);
    node_fused1<<<12500, 256, 0, stream>>>(rowptr, esrc, xl1, xr1, att1, b1, hbuf);

    // ---- layer 2 ----
    gemm_pair<64><<<1563, 256, 0, stream>>>(hbuf, Wl2, Wr2, xl1, xr1, N_NODES);
    node_fused2<<<12500, 256, 0, stream>>>(rowptr, esrc, xl1, xr1, att2, b2, out_emb);

    // ---- classifier ----
    classifier<<<1563, 256, 0, stream>>>(out_emb, Wc1, bc1, Wc2, bc2, out_logits);
}